// Round 12
// baseline (220.950 us; speedup 1.0000x reference)
//
#include <hip/hip_runtime.h>
#include <hip/hip_fp16.h>
#include <math.h>

#define DD 256
static constexpr int N_MET  = 2534;
static constexpr int N_RXN  = 4881;
static constexpr int N_GENE = 6607;
static constexpr int NE     = 262144;
static constexpr int NP     = 131072;

static constexpr int NCHUNK = 256;       // NE / 1024
static constexpr int NCHG   = 128;       // NP / 1024
static constexpr int NBE    = 77;        // edge buckets of 64
static constexpr int NBN    = 80;        // node buckets of 32
static constexpr int NBG    = 104;       // gene buckets of 64
static constexpr int CHS    = 80;        // chE/chN stride
static constexpr int NCOL   = NBE + NBN + NBG;          // 261 scan columns
static constexpr int GEMM_BLOCKS = (N_MET + 15) / 16;   // 159
static constexpr int KP2_GEMM0 = NBE + NBN + NBG;       // 261

static constexpr float SCL  = 2048.f;    // fp16 storage scale (linear pipeline)
static constexpr float SCLI = 1.f / 2048.f;

// ---------- wave reductions / broadcasts (64 lanes) ----------
__device__ __forceinline__ float waveSum(float v) {
  #pragma unroll
  for (int o = 32; o > 0; o >>= 1) v += __shfl_xor(v, o, 64);
  return v;
}
__device__ __forceinline__ float waveMax(float v) {
  #pragma unroll
  for (int o = 32; o > 0; o >>= 1) v = fmaxf(v, __shfl_xor(v, o, 64));
  return v;
}
__device__ __forceinline__ int   bcasti(int v, int l)   { return __builtin_amdgcn_readlane(v, l); }
__device__ __forceinline__ float bcastf(float v, int l) {
  return __int_as_float(__builtin_amdgcn_readlane(__float_as_int(v), l));
}

// ---------- fp16 pack/unpack ----------
__device__ __forceinline__ float4 h4f(uint2 u) {
  __half2 a = *reinterpret_cast<__half2*>(&u.x);
  __half2 b = *reinterpret_cast<__half2*>(&u.y);
  float2 fa = __half22float2(a), fb = __half22float2(b);
  return make_float4(fa.x, fa.y, fb.x, fb.y);
}
__device__ __forceinline__ uint2 f4h(float4 v) {
  __half2 a = __floats2half2_rn(v.x, v.y);
  __half2 b = __floats2half2_rn(v.z, v.w);
  uint2 u;
  u.x = *reinterpret_cast<unsigned*>(&a);
  u.y = *reinterpret_cast<unsigned*>(&b);
  return u;
}

// ---------- KH: vedot (blk 0..31) + global per-key hists + LDS bucket hists ----------
__global__ __launch_bounds__(1024) void KH_k(
    const int* __restrict__ he_node, const int* __restrict__ he_edge,
    const int* __restrict__ rtg_rxn, const int* __restrict__ rtg_gene,
    int* cntE, int* cntN, int* cntR, int* cntG,
    int* __restrict__ chE, int* __restrict__ chN, int* __restrict__ chG,
    const float* __restrict__ We0, const float* __restrict__ att0,
    const float* __restrict__ We1, const float* __restrict__ att1,
    float* __restrict__ ve0, float* __restrict__ ve1) {
  int blk = blockIdx.x, tid = threadIdx.x;
  if (blk < 32) {
    int wid = blk * 16 + (tid >> 6);   // 0..511
    int lane = tid & 63;
    const float* We = (wid < 256) ? We0 : We1;
    const float* at = (wid < 256) ? att0 : att1;
    int r = wid & 255;
    float4 a = ((const float4*)(We + (size_t)r * DD))[lane];
    float4 v = ((const float4*)(at + DD))[lane];
    float s = waveSum(a.x * v.x + a.y * v.y + a.z * v.z + a.w * v.w);
    if (lane == 0) ((wid < 256) ? ve0 : ve1)[r] = s;
    return;
  }
  int c = blk - 32;                     // chunk id, 0..255
  __shared__ int hE[NBE], hN[NBN], hG[NBG];
  if (tid < NBE) hE[tid] = 0;
  if (tid >= 128 && tid < 128 + NBN) hN[tid - 128] = 0;
  if (tid >= 256 && tid < 256 + NBG) hG[tid - 256] = 0;
  __syncthreads();
  int i = c * 1024 + tid;               // i < NE always
  int n = he_node[i], e = he_edge[i];
  atomicAdd(&cntE[e], 1); atomicAdd(&cntN[n], 1);
  atomicAdd(&hE[e >> 6], 1); atomicAdd(&hN[n >> 5], 1);
  if (c < NCHG) {
    int r = rtg_rxn[i], g = rtg_gene[i];
    atomicAdd(&cntR[r], 1); atomicAdd(&cntG[g], 1);
    atomicAdd(&hG[g >> 6], 1);
  }
  __syncthreads();
  if (tid < NBE) chE[c * CHS + tid] = hE[tid];
  if (tid >= 128 && tid < 128 + NBN) chN[c * CHS + (tid - 128)] = hN[tid - 128];
  if (c < NCHG && tid >= 256 && tid < 256 + NBG) chG[c * NBG + (tid - 256)] = hG[tid - 256];
}

// ---------- KScan: big scans (blk 0-2) + column scans (blk 3-19) + gdot ----------
__global__ __launch_bounds__(1024) void KScan_k(
    const int* __restrict__ cntE, int* __restrict__ offsE,
    const int* __restrict__ cntN, int* __restrict__ offsN,
    const int* __restrict__ cntG, int* __restrict__ offsG,
    int* __restrict__ chE, int* __restrict__ chN, int* __restrict__ chG,
    const float* __restrict__ gene_x,
    const float* __restrict__ ve0, const float* __restrict__ ve1,
    float* __restrict__ gdot0, float* __restrict__ gdot1) {
  int blk = blockIdx.x, tid = threadIdx.x;
  if (blk < 3) {
    const int* cnt; int n; int* offs;
    if      (blk == 0) { cnt = cntE; n = N_RXN;  offs = offsE; }
    else if (blk == 1) { cnt = cntN; n = N_MET;  offs = offsN; }
    else               { cnt = cntG; n = N_GENE; offs = offsG; }
    __shared__ int part[1024];
    int base = tid * 8;
    int v[8]; int s = 0;
    #pragma unroll
    for (int j = 0; j < 8; ++j) { int x = (base + j < n) ? cnt[base + j] : 0; v[j] = x; s += x; }
    part[tid] = s;
    __syncthreads();
    for (int o = 1; o < 1024; o <<= 1) {
      int t = (tid >= o) ? part[tid - o] : 0;
      __syncthreads();
      part[tid] += t;
      __syncthreads();
    }
    int ex = part[tid] - s;
    #pragma unroll
    for (int j = 0; j < 8; ++j) {
      if (base + j < n) { offs[base + j] = ex; ex += v[j]; }
    }
    if (tid == 1023) offs[n] = part[1023];
    return;
  }
  if (blk < 20) {
    int colw = (blk - 3) * 16 + (tid >> 6);
    int lane = tid & 63;
    if (colw >= NCOL) return;
    if (colw < NBE + NBN) {
      int side = colw >= NBE;
      int b = colw - side * NBE;
      int* ch = side ? chN : chE;
      int v[4]; int s = 0;
      int cbase = lane * 4;
      #pragma unroll
      for (int k = 0; k < 4; ++k) { v[k] = ch[(cbase + k) * CHS + b]; s += v[k]; }
      int inc = s;
      #pragma unroll
      for (int o = 1; o < 64; o <<= 1) { int t = __shfl_up(inc, o, 64); if (lane >= o) inc += t; }
      int ex = inc - s;
      #pragma unroll
      for (int k = 0; k < 4; ++k) { int t = v[k]; ch[(cbase + k) * CHS + b] = ex; ex += t; }
    } else {
      int b = colw - NBE - NBN;
      int v[2]; int s = 0;
      int cbase = lane * 2;
      #pragma unroll
      for (int k = 0; k < 2; ++k) { v[k] = chG[(cbase + k) * NBG + b]; s += v[k]; }
      int inc = s;
      #pragma unroll
      for (int o = 1; o < 64; o <<= 1) { int t = __shfl_up(inc, o, 64); if (lane >= o) inc += t; }
      int ex = inc - s;
      #pragma unroll
      for (int k = 0; k < 2; ++k) { int t = v[k]; chG[(cbase + k) * NBG + b] = ex; ex += t; }
    }
    return;
  }
  // gdot
  int wid = (blk - 20) * 16 + (tid >> 6);
  int lane = tid & 63;
  if (wid >= N_GENE) return;
  float4 a  = ((const float4*)gene_x)[(size_t)wid * 64 + lane];
  float4 v0 = ((const float4*)ve0)[lane];
  float4 v1 = ((const float4*)ve1)[lane];
  float s0 = waveSum(a.x * v0.x + a.y * v0.y + a.z * v0.z + a.w * v0.w);
  float s1 = waveSum(a.x * v1.x + a.y * v1.y + a.z * v1.z + a.w * v1.w);
  if (lane == 0) { gdot0[wid] = s0; gdot1[wid] = s1; }
}

// ---------- KP1: bucket partition (packed 8B/4B records, bases from offs) + se ----------
__global__ __launch_bounds__(1024) void KP1_k(
    const int* __restrict__ he_node, const int* __restrict__ he_edge,
    const float* __restrict__ stoich,
    const int* __restrict__ offsE, const int* __restrict__ offsN,
    const int* __restrict__ offsG,
    const int* __restrict__ chE, const int* __restrict__ chN,
    const int* __restrict__ chG,
    int2* __restrict__ scrE, int2* __restrict__ scrN, int* __restrict__ scrG,
    const int* __restrict__ rtg_rxn, const int* __restrict__ rtg_gene,
    const float* __restrict__ gdot0, const float* __restrict__ gdot1,
    float* __restrict__ seAcc0, float* __restrict__ seAcc1) {
  int c = blockIdx.x, tid = threadIdx.x;
  __shared__ int cursE[NBE], cursN[NBN], cursG[NBG];
  if (tid < NBE) cursE[tid] = offsE[64 * tid] + chE[c * CHS + tid];
  if (tid >= 128 && tid < 128 + NBN) {
    int t = tid - 128;
    cursN[t] = offsN[32 * t] + chN[c * CHS + t];
  }
  if (c < NCHG && tid >= 256 && tid < 256 + NBG) {
    int t = tid - 256;
    cursG[t] = offsG[64 * t] + chG[c * NBG + t];
  }
  __syncthreads();
  int i = c * 1024 + tid;
  int n = he_node[i], e = he_edge[i];
  int st = __float_as_int(stoich[i]);
  int dE = atomicAdd(&cursE[e >> 6], 1);
  scrE[dE] = make_int2((e << 12) | n, st);
  int dN = atomicAdd(&cursN[n >> 5], 1);
  scrN[dN] = make_int2((n << 13) | e, st);
  if (c < NCHG) {
    int r = rtg_rxn[i], g = rtg_gene[i];
    int dG = atomicAdd(&cursG[g >> 6], 1);
    scrG[dG] = (g << 13) | r;
    atomicAdd(&seAcc0[r], gdot0[g]);
    atomicAdd(&seAcc1[r], gdot1[g]);
  }
}

// ---------- GEMM body: Y(half,scaled) = X @ W; optional renorm; fused sn(f32) ----------
template <bool RENORM, bool XH>
__device__ __forceinline__ void gemm_body(const void* __restrict__ Xv,
                                          const float* __restrict__ W,
                                          const float* __restrict__ att,
                                          __half* __restrict__ Y,
                                          float* __restrict__ sn, int M, int r0) {
  __shared__ float Xs[256][20];
  __shared__ float red[4][16];
  __shared__ float scl[16];
  int tid = threadIdx.x;
  int w = tid >> 6, lane = tid & 63;
  float xv[16];
  #pragma unroll
  for (int i = 0; i < 16; ++i) {
    int r = r0 + i;
    if (r < M) {
      if (XH) xv[i] = __half2float(((const __half*)Xv)[(size_t)r * DD + tid]);
      else    xv[i] = ((const float*)Xv)[(size_t)r * DD + tid];
    } else xv[i] = 0.f;
  }
  if (RENORM) {
    #pragma unroll
    for (int i = 0; i < 16; ++i) {
      float v = waveSum(xv[i] * xv[i]);
      if (lane == 0) red[w][i] = v;
    }
    __syncthreads();
    if (tid < 16) {
      float t = red[0][tid] + red[1][tid] + red[2][tid] + red[3][tid];
      scl[tid] = fminf(1.f, 1.f / (sqrtf(t) + 1e-12f));
    }
    __syncthreads();
    #pragma unroll
    for (int i = 0; i < 16; ++i) xv[i] *= scl[i];
  }
  #pragma unroll
  for (int i = 0; i < 16; ++i) Xs[tid][i] = xv[i];
  __syncthreads();
  float acc[16];
  #pragma unroll
  for (int i = 0; i < 16; ++i) acc[i] = 0.f;
  const float* wp = W + tid;
  #pragma unroll 8
  for (int k = 0; k < 256; ++k) {
    float wv = wp[(size_t)k * DD];
    const float4* xr = reinterpret_cast<const float4*>(&Xs[k][0]);
    float4 a0 = xr[0], a1 = xr[1], a2 = xr[2], a3 = xr[3];
    acc[0]  += a0.x * wv; acc[1]  += a0.y * wv; acc[2]  += a0.z * wv; acc[3]  += a0.w * wv;
    acc[4]  += a1.x * wv; acc[5]  += a1.y * wv; acc[6]  += a1.z * wv; acc[7]  += a1.w * wv;
    acc[8]  += a2.x * wv; acc[9]  += a2.y * wv; acc[10] += a2.z * wv; acc[11] += a2.w * wv;
    acc[12] += a3.x * wv; acc[13] += a3.y * wv; acc[14] += a3.z * wv; acc[15] += a3.w * wv;
  }
  const float ysc = XH ? 1.f : SCL;
  #pragma unroll
  for (int i = 0; i < 16; ++i) {
    int r = r0 + i;
    if (r < M) Y[(size_t)r * DD + tid] = __float2half_rn(acc[i] * ysc);
  }
  float av = att[tid];
  __syncthreads();
  #pragma unroll
  for (int i = 0; i < 16; ++i) {
    float v = waveSum(acc[i] * av);
    if (lane == 0) red[w][i] = v;
  }
  __syncthreads();
  if (tid < 16) {
    int r = r0 + tid;
    if (r < M) sn[r] = (red[0][tid] + red[1][tid] + red[2][tid] + red[3][tid])
                       * (XH ? SCLI : 1.f);
  }
}

// ---------- KP2: single-pass CSR placement (curs from offs) + gemm0 ----------
__global__ __launch_bounds__(256) void KP2_k(
    const int* __restrict__ offsE, const int* __restrict__ offsN,
    const int* __restrict__ offsG,
    const int2* __restrict__ scrE, const int2* __restrict__ scrN,
    const int* __restrict__ scrG,
    int2* __restrict__ payE, int2* __restrict__ payN, int* __restrict__ rxnG,
    const float* __restrict__ emb, const float* __restrict__ W0,
    const float* __restrict__ att0, __half* __restrict__ xp,
    float* __restrict__ sn) {
  int blk = blockIdx.x, tid = threadIdx.x;
  if (blk >= KP2_GEMM0) {
    gemm_body<true, false>(emb, W0, att0, xp, sn, N_MET, (blk - KP2_GEMM0) * 16);
    return;
  }
  if (blk < NBE) {
    __shared__ int curs[64];
    int elo = 64 * blk;
    int ecnt = min(64, N_RXN - elo);
    if (tid < ecnt) curs[tid] = offsE[elo + tid];
    __syncthreads();
    int lo = offsE[elo], hi = offsE[elo + ecnt];
    for (int j = lo + tid; j < hi; j += 256) {
      int2 r = scrE[j];
      int e = r.x >> 12, n = r.x & 4095;
      int slot = atomicAdd(&curs[e - elo], 1);
      payE[slot] = make_int2(n, r.y);
    }
  } else if (blk < NBE + NBN) {
    __shared__ int curs[32];
    int b = blk - NBE;
    int nlo = 32 * b;
    int ncnt = min(32, N_MET - nlo);
    if (tid < ncnt) curs[tid] = offsN[nlo + tid];
    __syncthreads();
    int lo = offsN[nlo], hi = offsN[nlo + ncnt];
    for (int j = lo + tid; j < hi; j += 256) {
      int2 r = scrN[j];
      int n = r.x >> 13, e = r.x & 8191;
      int slot = atomicAdd(&curs[n - nlo], 1);
      payN[slot] = make_int2(e, r.y);
    }
  } else {
    __shared__ int curs[64];
    int b = blk - NBE - NBN;
    int glo = 64 * b;
    int gcnt = min(64, N_GENE - glo);
    if (tid < gcnt) curs[tid] = offsG[glo + tid];
    __syncthreads();
    int lo = offsG[glo], hi = offsG[glo + gcnt];
    for (int j = lo + tid; j < hi; j += 256) {
      int pw = scrG[j];
      int g = pw >> 13, rr = pw & 8191;
      int slot = atomicAdd(&curs[g - glo], 1);
      rxnG[slot] = rr;
    }
  }
}

// standalone gemm (layer 1): X = cur (half, scaled)
__global__ __launch_bounds__(256) void gemm1_k(const __half* __restrict__ X,
                                               const float* __restrict__ W,
                                               const float* __restrict__ att,
                                               __half* __restrict__ Y,
                                               float* __restrict__ sn, int M) {
  gemm_body<false, true>(X, W, att, Y, sn, M, blockIdx.x * 16);
}

// ---------- 16-deep weighted gather-accumulate over fp16 rows (readlane bcast) ----------
__device__ __forceinline__ void gatherAccH(float4& acc, const uint2* __restrict__ src,
                                           const int (&rv)[4], const float (&wv)[4],
                                           int nc, int lane) {
  #pragma unroll
  for (int c = 0; c < 4; ++c) {
    int lim = nc - c * 64; if (lim > 64) lim = 64;
    for (int t = 0; t < lim; t += 16) {
      uint2 a[16]; float w[16];
      #pragma unroll
      for (int q = 0; q < 16; ++q) {
        int   n = bcasti(rv[c], t + q);
        w[q]    = bcastf(wv[c], t + q);
        a[q]    = src[(size_t)n * 64 + lane];
      }
      #pragma unroll
      for (int q = 0; q < 16; ++q) {
        float4 f = h4f(a[q]);
        acc.x += w[q] * f.x; acc.y += w[q] * f.y;
        acc.z += w[q] * f.z; acc.w += w[q] * f.w;
      }
    }
  }
}

// ---------- segment mean (wave per segment), fp16 rows ----------
template <int STRIDE, bool F32OUT>
__global__ __launch_bounds__(256) void seg_mean_k(const int* __restrict__ offs,
                                                  const int* __restrict__ pay,
                                                  const uint2* __restrict__ src,
                                                  void* __restrict__ dst, int nseg) {
  int wid = (blockIdx.x * 256 + threadIdx.x) >> 6;
  int lane = threadIdx.x & 63;
  if (wid >= nseg) return;
  int beg = offs[wid], end = offs[wid + 1];
  int cnt = end - beg;
  int nc = cnt < 256 ? cnt : 256;
  int rv[4]; float wv[4];
  #pragma unroll
  for (int c = 0; c < 4; ++c) {
    int j = c * 64 + lane;
    if (j < nc) { rv[c] = pay[(size_t)(beg + j) * STRIDE]; wv[c] = 1.f; }
    else        { rv[c] = 0;                               wv[c] = 0.f; }
  }
  float4 acc = make_float4(0.f, 0.f, 0.f, 0.f);
  gatherAccH(acc, src, rv, wv, nc, lane);
  for (int j = 256; j < cnt; ++j) {
    int n = pay[(size_t)(beg + j) * STRIDE];
    float4 a = h4f(src[(size_t)n * 64 + lane]);
    acc.x += a.x; acc.y += a.y; acc.z += a.z; acc.w += a.w;
  }
  float inv = 1.f / (float)(cnt > 1 ? cnt : 1);
  float4 o; o.x = acc.x * inv; o.y = acc.y * inv; o.z = acc.z * inv; o.w = acc.w * inv;
  if (F32OUT) {
    o.x *= SCLI; o.y *= SCLI; o.z *= SCLI; o.w *= SCLI;
    ((float4*)dst)[(size_t)wid * 64 + lane] = o;
  } else {
    ((uint2*)dst)[(size_t)wid * 64 + lane] = f4h(o);
  }
}

// ---------- me: wave per reaction; softmax (f32) + fp16-row gather ----------
__global__ __launch_bounds__(256) void me_k(const int* __restrict__ offs,
                                            const int2* __restrict__ payE,
                                            const float* __restrict__ sn,
                                            const float* __restrict__ seAcc,
                                            const int* __restrict__ cntR,
                                            const uint2* __restrict__ xp,
                                            uint2* __restrict__ me,
                                            float4* __restrict__ rstat) {
  int wid = (blockIdx.x * 256 + threadIdx.x) >> 6;
  int lane = threadIdx.x & 63;
  if (wid >= N_RXN) return;
  int rc = cntR[wid];
  float ser = seAcc[wid] / (float)(rc > 1 ? rc : 1);

  int beg = offs[wid], end = offs[wid + 1];
  int cnt = end - beg;
  int nc = cnt < 256 ? cnt : 256;
  int nv[4]; float wv[4]; float stv[4];
  float lmax = -1e30f;
  #pragma unroll
  for (int c = 0; c < 4; ++c) {
    int j = c * 64 + lane;
    if (j < nc) {
      int2 p = payE[beg + j];
      float l = sn[p.x] + ser;
      l = (l >= 0.f) ? l : 0.2f * l;
      nv[c] = p.x; wv[c] = l; stv[c] = __int_as_float(p.y);
      lmax = fmaxf(lmax, l);
    } else { nv[c] = 0; wv[c] = -1e30f; stv[c] = 0.f; }
  }
  for (int j = 256 + lane; j < cnt; j += 64) {
    int2 p = payE[beg + j];
    float l = sn[p.x] + ser;
    l = (l >= 0.f) ? l : 0.2f * l;
    lmax = fmaxf(lmax, l);
  }
  float m = waveMax(lmax);
  float s = 0.f;
  #pragma unroll
  for (int c = 0; c < 4; ++c) {
    if (c * 64 + lane < nc) { float e = expf(wv[c] - m); wv[c] = e; s += e; }
    else wv[c] = 0.f;
  }
  for (int j = 256 + lane; j < cnt; j += 64) {
    int2 p = payE[beg + j];
    float l = sn[p.x] + ser;
    l = (l >= 0.f) ? l : 0.2f * l;
    s += expf(l - m);
  }
  s = waveSum(s);
  float invS = 1.f / (s + 1e-16f);
  #pragma unroll
  for (int c = 0; c < 4; ++c) {
    if (c * 64 + lane < nc) wv[c] = stv[c] * wv[c] * invS;
  }
  if (lane == 0) rstat[wid] = make_float4(ser, m, invS, 0.f);
  float4 acc = make_float4(0.f, 0.f, 0.f, 0.f);
  gatherAccH(acc, xp, nv, wv, nc, lane);
  for (int j = 256; j < cnt; ++j) {
    int2 p = payE[beg + j];
    float l = sn[p.x] + ser;
    l = (l >= 0.f) ? l : 0.2f * l;
    float w = __int_as_float(p.y) * expf(l - m) * invS;
    float4 a = h4f(xp[(size_t)p.x * 64 + lane]);
    acc.x += w * a.x; acc.y += w * a.y; acc.z += w * a.z; acc.w += w * a.w;
  }
  float invB = 1.f / (float)(cnt > 1 ? cnt : 1);
  float4 o; o.x = acc.x * invB; o.y = acc.y * invB; o.z = acc.z * invB; o.w = acc.w * invB;
  me[(size_t)wid * 64 + lane] = f4h(o);   // stays scaled by SCL
}

// ---------- out: wave per metabolite; fp16-row gather + tanh (+ skip + LN) ----------
template <bool LN>
__global__ __launch_bounds__(256) void out_k(const int* __restrict__ offs,
                                             const int2* __restrict__ payN,
                                             const float* __restrict__ sn,
                                             const float4* __restrict__ rstat,
                                             const uint2* __restrict__ me,
                                             const float* __restrict__ bias,
                                             const float* __restrict__ ln_g,
                                             const float* __restrict__ ln_b,
                                             uint2* __restrict__ cur) {
  int wid = (blockIdx.x * 256 + threadIdx.x) >> 6;
  int lane = threadIdx.x & 63;
  if (wid >= N_MET) return;
  int beg = offs[wid], end = offs[wid + 1];
  int cnt = end - beg;
  int nc = cnt < 256 ? cnt : 256;
  float sn_n = sn[wid];
  int rv[4]; float wv[4];
  #pragma unroll
  for (int c = 0; c < 4; ++c) {
    int j = c * 64 + lane;
    if (j < nc) {
      int2 p = payN[beg + j];
      float4 st = rstat[p.x];
      float l = sn_n + st.x;
      l = (l >= 0.f) ? l : 0.2f * l;
      rv[c] = p.x;
      wv[c] = __int_as_float(p.y) * expf(l - st.y) * st.z;
    } else { rv[c] = 0; wv[c] = 0.f; }
  }
  float4 acc = make_float4(0.f, 0.f, 0.f, 0.f);
  gatherAccH(acc, me, rv, wv, nc, lane);
  for (int j = 256; j < cnt; ++j) {
    int2 p = payN[beg + j];
    float4 st = rstat[p.x];
    float l = sn_n + st.x;
    l = (l >= 0.f) ? l : 0.2f * l;
    float w = __int_as_float(p.y) * expf(l - st.y) * st.z;
    float4 a = h4f(me[(size_t)p.x * 64 + lane]);
    acc.x += w * a.x; acc.y += w * a.y; acc.z += w * a.z; acc.w += w * a.w;
  }
  float invD = SCLI / (float)(cnt > 1 ? cnt : 1);   // unscale + mean
  float4 b4 = ((const float4*)bias)[lane];
  float4 o;                                          // unscaled f32 tanh output
  o.x = tanhf(acc.x * invD + b4.x);
  o.y = tanhf(acc.y * invD + b4.y);
  o.z = tanhf(acc.z * invD + b4.z);
  o.w = tanhf(acc.w * invD + b4.w);
  if (!LN) {
    float4 so; so.x = o.x * SCL; so.y = o.y * SCL; so.z = o.z * SCL; so.w = o.w * SCL;
    cur[(size_t)wid * 64 + lane] = f4h(so);
    return;
  }
  float4 p = h4f(cur[(size_t)wid * 64 + lane]);
  p.x *= SCLI; p.y *= SCLI; p.z *= SCLI; p.w *= SCLI;   // unscale skip
  float4 z; z.x = o.x + p.x; z.y = o.y + p.y; z.z = o.z + p.z; z.w = o.w + p.w;
  float mu = waveSum(z.x + z.y + z.z + z.w) * (1.f / 256.f);
  float4 zc; zc.x = z.x - mu; zc.y = z.y - mu; zc.z = z.z - mu; zc.w = z.w - mu;
  float var = waveSum(zc.x * zc.x + zc.y * zc.y + zc.z * zc.z + zc.w * zc.w) * (1.f / 256.f);
  float rs = 1.f / sqrtf(var + 1e-5f);
  float4 g4 = ((const float4*)ln_g)[lane];
  float4 be4 = ((const float4*)ln_b)[lane];
  float4 r;
  r.x = (zc.x * rs * g4.x + be4.x) * SCL;
  r.y = (zc.y * rs * g4.y + be4.y) * SCL;
  r.z = (zc.z * rs * g4.z + be4.z) * SCL;
  r.w = (zc.w * rs * g4.w + be4.w) * SCL;
  cur[(size_t)wid * 64 + lane] = f4h(r);
}

// ---------- launcher ----------
extern "C" void kernel_launch(void* const* d_in, const int* in_sizes, int n_in,
                              void* d_out, int out_size, void* d_ws, size_t ws_size,
                              hipStream_t stream) {
  const int*   he_node = (const int*)d_in[0];
  const int*   he_edge = (const int*)d_in[1];
  const float* stoich  = (const float*)d_in[2];
  const float* gene_x  = (const float*)d_in[3];
  const int*   rtg_rxn = (const int*)d_in[4];
  const int*   rtg_gene= (const int*)d_in[5];
  const float* emb     = (const float*)d_in[6];
  const float* W0      = (const float*)d_in[7];
  const float* We0     = (const float*)d_in[8];
  const float* att0    = (const float*)d_in[9];
  const float* b0      = (const float*)d_in[10];
  const float* W1      = (const float*)d_in[11];
  const float* We1     = (const float*)d_in[12];
  const float* att1    = (const float*)d_in[13];
  const float* b1      = (const float*)d_in[14];
  const float* ln_g    = (const float*)d_in[15];
  const float* ln_b    = (const float*)d_in[16];
  float* out = (float*)d_out;

  char* base = (char*)d_ws;
  size_t off = 0;
  auto carve = [&](size_t bytes) -> char* {
    char* p = base + off;
    off += (bytes + 255) & ~(size_t)255;
    return p;
  };
  __half* xp_h   = (__half*)carve((size_t)N_MET * DD * 2);
  __half* me_h   = (__half*)carve((size_t)N_RXN * DD * 2);
  __half* cur_h  = (__half*)carve((size_t)N_MET * DD * 2);
  __half* rxnf_h = (__half*)carve((size_t)N_RXN * DD * 2);
  float*  sn    = (float*)carve((size_t)N_MET * 4);
  float*  ve0   = (float*)carve(DD * 4);
  float*  ve1   = (float*)carve(DD * 4);
  float*  gdot0 = (float*)carve((size_t)N_GENE * 4);
  float*  gdot1 = (float*)carve((size_t)N_GENE * 4);
  float4* rstat = (float4*)carve((size_t)N_RXN * 16);
  // zeroed region: cntE, cntN, cntR, cntG, seAcc0, seAcc1
  int ztot = N_RXN + N_MET + N_RXN + N_GENE + 2 * N_RXN;
  int* zbase = (int*)carve((size_t)ztot * 4);
  int*   cntE   = zbase;
  int*   cntN   = cntE + N_RXN;
  int*   cntR   = cntN + N_MET;
  int*   cntG   = cntR + N_RXN;
  float* seAcc0 = (float*)(cntG + N_GENE);
  float* seAcc1 = seAcc0 + N_RXN;
  int*  offsE = (int*)carve((N_RXN + 1) * 4);
  int2* payE  = (int2*)carve((size_t)NE * 8);
  int*  offsN = (int*)carve((N_MET + 1) * 4);
  int2* payN  = (int2*)carve((size_t)NE * 8);
  int*  offsG = (int*)carve((N_GENE + 1) * 4);
  int*  rxnG  = (int*)carve((size_t)NP * 4);
  int2* scrE  = (int2*)carve((size_t)NE * 8);
  int2* scrN  = (int2*)carve((size_t)NE * 8);
  int*  scrG  = (int*)carve((size_t)NP * 4);
  int*  chE   = (int*)carve((size_t)NCHUNK * CHS * 4);
  int*  chN   = (int*)carve((size_t)NCHUNK * CHS * 4);
  int*  chG   = (int*)carve((size_t)NCHG * NBG * 4);

  hipMemsetAsync(zbase, 0, (size_t)ztot * 4, stream);

  // KH: vedot + global per-key hists + LDS bucket hists
  KH_k<<<32 + NCHUNK, 1024, 0, stream>>>(
      he_node, he_edge, rtg_rxn, rtg_gene, cntE, cntN, cntR, cntG,
      chE, chN, chG, We0, att0, We1, att1, ve0, ve1);

  // KScan: big scans (offs) + column scans + gdot
  int gdot_blocks = (N_GENE + 15) / 16;
  KScan_k<<<20 + gdot_blocks, 1024, 0, stream>>>(
      cntE, offsE, cntN, offsN, cntG, offsG,
      chE, chN, chG, gene_x, ve0, ve1, gdot0, gdot1);

  // KP1: bucket partition (packed records, bases from offs) + se atomics
  KP1_k<<<NCHUNK, 1024, 0, stream>>>(
      he_node, he_edge, stoich, offsE, offsN, offsG, chE, chN, chG,
      scrE, scrN, scrG, rtg_rxn, rtg_gene, gdot0, gdot1, seAcc0, seAcc1);

  // KP2: single-pass CSR placement + gemm0 (xp fp16)
  KP2_k<<<KP2_GEMM0 + GEMM_BLOCKS, 256, 0, stream>>>(
      offsE, offsN, offsG, scrE, scrN, scrG,
      payE, payN, rxnG, emb, W0, att0, xp_h, sn);

  // layer 0
  me_k<<<(N_RXN + 3) / 4, 256, 0, stream>>>(offsE, payE, sn, seAcc0, cntR,
                                            (const uint2*)xp_h, (uint2*)me_h, rstat);
  out_k<false><<<(N_MET + 3) / 4, 256, 0, stream>>>(offsN, payN, sn, rstat,
                                                    (const uint2*)me_h, b0,
                                                    nullptr, nullptr, (uint2*)cur_h);

  // layer 1
  gemm1_k<<<GEMM_BLOCKS, 256, 0, stream>>>(cur_h, W1, att1, xp_h, sn, N_MET);
  me_k<<<(N_RXN + 3) / 4, 256, 0, stream>>>(offsE, payE, sn, seAcc1, cntR,
                                            (const uint2*)xp_h, (uint2*)me_h, rstat);
  out_k<true><<<(N_MET + 3) / 4, 256, 0, stream>>>(offsN, payN, sn, rstat,
                                                   (const uint2*)me_h, b1,
                                                   ln_g, ln_b, (uint2*)cur_h);

  // final readout
  seg_mean_k<2, false><<<(N_RXN + 3) / 4, 256, 0, stream>>>(
      offsE, (const int*)payE, (const uint2*)cur_h, rxnf_h, N_RXN);
  seg_mean_k<1, true><<<(N_GENE + 3) / 4, 256, 0, stream>>>(
      offsG, rxnG, (const uint2*)rxnf_h, out, N_GENE);
}

// Round 13
// 202.936 us; speedup vs baseline: 1.0888x; 1.0888x over previous
//
#include <hip/hip_runtime.h>
#include <hip/hip_fp16.h>
#include <math.h>

#define DD 256
static constexpr int N_MET  = 2534;
static constexpr int N_RXN  = 4881;
static constexpr int N_GENE = 6607;
static constexpr int NE     = 262144;
static constexpr int NP     = 131072;

static constexpr int NCHUNK = 256;       // NE / 1024
static constexpr int NCHG   = 128;       // NP / 1024
static constexpr int NBE    = 306;       // edge buckets of 16 keys
static constexpr int NBN    = 317;       // node buckets of 8 keys
static constexpr int NBG    = 413;       // gene buckets of 16 keys
static constexpr int NCOL   = NBE + NBN + NBG;          // 1036 scan columns
static constexpr int GEMM_BLOCKS = (N_MET + 15) / 16;   // 159
static constexpr int KP2_GEMM0 = NBE + NBN + NBG;       // 1036

static constexpr float SCL  = 2048.f;    // fp16 storage scale (linear pipeline)
static constexpr float SCLI = 1.f / 2048.f;

// ---------- wave reductions / broadcasts (64 lanes) ----------
__device__ __forceinline__ float waveSum(float v) {
  #pragma unroll
  for (int o = 32; o > 0; o >>= 1) v += __shfl_xor(v, o, 64);
  return v;
}
__device__ __forceinline__ float waveMax(float v) {
  #pragma unroll
  for (int o = 32; o > 0; o >>= 1) v = fmaxf(v, __shfl_xor(v, o, 64));
  return v;
}
__device__ __forceinline__ int   bcasti(int v, int l)   { return __builtin_amdgcn_readlane(v, l); }
__device__ __forceinline__ float bcastf(float v, int l) {
  return __int_as_float(__builtin_amdgcn_readlane(__float_as_int(v), l));
}

// ---------- fp16 pack/unpack ----------
__device__ __forceinline__ float4 h4f(uint2 u) {
  __half2 a = *reinterpret_cast<__half2*>(&u.x);
  __half2 b = *reinterpret_cast<__half2*>(&u.y);
  float2 fa = __half22float2(a), fb = __half22float2(b);
  return make_float4(fa.x, fa.y, fb.x, fb.y);
}
__device__ __forceinline__ uint2 f4h(float4 v) {
  __half2 a = __floats2half2_rn(v.x, v.y);
  __half2 b = __floats2half2_rn(v.z, v.w);
  uint2 u;
  u.x = *reinterpret_cast<unsigned*>(&a);
  u.y = *reinterpret_cast<unsigned*>(&b);
  return u;
}

// ---------- KH: vedot (blk 0..31) + LDS bucket hists + cntR (blk 32..287) ----------
__global__ __launch_bounds__(1024) void KH_k(
    const int* __restrict__ he_node, const int* __restrict__ he_edge,
    const int* __restrict__ rtg_rxn, const int* __restrict__ rtg_gene,
    int* cntR,
    int* __restrict__ chE, int* __restrict__ chN, int* __restrict__ chG,
    const float* __restrict__ We0, const float* __restrict__ att0,
    const float* __restrict__ We1, const float* __restrict__ att1,
    float* __restrict__ ve0, float* __restrict__ ve1) {
  int blk = blockIdx.x, tid = threadIdx.x;
  if (blk < 32) {
    int wid = blk * 16 + (tid >> 6);   // 0..511
    int lane = tid & 63;
    const float* We = (wid < 256) ? We0 : We1;
    const float* at = (wid < 256) ? att0 : att1;
    int r = wid & 255;
    float4 a = ((const float4*)(We + (size_t)r * DD))[lane];
    float4 v = ((const float4*)(at + DD))[lane];
    float s = waveSum(a.x * v.x + a.y * v.y + a.z * v.z + a.w * v.w);
    if (lane == 0) ((wid < 256) ? ve0 : ve1)[r] = s;
    return;
  }
  int c = blk - 32;                     // chunk id, 0..255
  __shared__ int hE[NBE], hN[NBN], hG[NBG];
  if (tid < NBE) hE[tid] = 0;
  if (tid < NBN) hN[tid] = 0;
  if (tid < NBG) hG[tid] = 0;
  __syncthreads();
  int i = c * 1024 + tid;               // i < NE always
  int n = he_node[i], e = he_edge[i];
  atomicAdd(&hE[e >> 4], 1); atomicAdd(&hN[n >> 3], 1);
  if (c < NCHG) {
    int r = rtg_rxn[i], g = rtg_gene[i];
    atomicAdd(&cntR[r], 1);
    atomicAdd(&hG[g >> 4], 1);
  }
  __syncthreads();
  if (tid < NBE) chE[c * NBE + tid] = hE[tid];
  if (tid < NBN) chN[c * NBN + tid] = hN[tid];
  if (c < NCHG && tid < NBG) chG[c * NBG + tid] = hG[tid];
}

// ---------- KScan: column scans (blk 0..64, emit bucket totals) + gdot ----------
__global__ __launch_bounds__(1024) void KScan_k(
    int* __restrict__ chE, int* __restrict__ chN, int* __restrict__ chG,
    int* __restrict__ totE, int* __restrict__ totN, int* __restrict__ totG,
    const float* __restrict__ gene_x,
    const float* __restrict__ ve0, const float* __restrict__ ve1,
    float* __restrict__ gdot0, float* __restrict__ gdot1) {
  int blk = blockIdx.x, tid = threadIdx.x;
  if (blk < 65) {
    int colw = blk * 16 + (tid >> 6);
    int lane = tid & 63;
    if (colw >= NCOL) return;
    if (colw < NBE + NBN) {
      int side = colw >= NBE;
      int b = colw - side * NBE;
      int* ch = side ? chN : chE;
      int* tot = side ? totN : totE;
      int stride = side ? NBN : NBE;
      int v[4]; int s = 0;
      int cbase = lane * 4;
      #pragma unroll
      for (int k = 0; k < 4; ++k) { v[k] = ch[(size_t)(cbase + k) * stride + b]; s += v[k]; }
      int inc = s;
      #pragma unroll
      for (int o = 1; o < 64; o <<= 1) { int t = __shfl_up(inc, o, 64); if (lane >= o) inc += t; }
      if (lane == 63) tot[b] = inc;
      int ex = inc - s;
      #pragma unroll
      for (int k = 0; k < 4; ++k) { int t = v[k]; ch[(size_t)(cbase + k) * stride + b] = ex; ex += t; }
    } else {
      int b = colw - NBE - NBN;
      int v[2]; int s = 0;
      int cbase = lane * 2;
      #pragma unroll
      for (int k = 0; k < 2; ++k) { v[k] = chG[(size_t)(cbase + k) * NBG + b]; s += v[k]; }
      int inc = s;
      #pragma unroll
      for (int o = 1; o < 64; o <<= 1) { int t = __shfl_up(inc, o, 64); if (lane >= o) inc += t; }
      if (lane == 63) totG[b] = inc;
      int ex = inc - s;
      #pragma unroll
      for (int k = 0; k < 2; ++k) { int t = v[k]; chG[(size_t)(cbase + k) * NBG + b] = ex; ex += t; }
    }
    return;
  }
  // gdot
  int wid = (blk - 65) * 16 + (tid >> 6);
  int lane = tid & 63;
  if (wid >= N_GENE) return;
  float4 a  = ((const float4*)gene_x)[(size_t)wid * 64 + lane];
  float4 v0 = ((const float4*)ve0)[lane];
  float4 v1 = ((const float4*)ve1)[lane];
  float s0 = waveSum(a.x * v0.x + a.y * v0.y + a.z * v0.z + a.w * v0.w);
  float s1 = waveSum(a.x * v1.x + a.y * v1.y + a.z * v1.z + a.w * v1.w);
  if (lane == 0) { gdot0[wid] = s0; gdot1[wid] = s1; }
}

// ---------- KBase: exclusive scans of bucket totals -> base arrays (1 block) ----------
__device__ __forceinline__ void scanOne512(const int* __restrict__ tot, int n,
                                           int* __restrict__ base, int* sc, int tid) {
  int v = 0;
  if (tid < 512) { v = (tid < n) ? tot[tid] : 0; sc[tid] = v; }
  __syncthreads();
  #pragma unroll
  for (int o = 1; o < 512; o <<= 1) {
    int t = (tid < 512 && tid >= o) ? sc[tid - o] : 0;
    __syncthreads();
    if (tid < 512) sc[tid] += t;
    __syncthreads();
  }
  if (tid < n) base[tid] = sc[tid] - v;
  if (tid == 0) base[n] = sc[511];
  __syncthreads();
}

__global__ __launch_bounds__(512) void KBase_k(
    const int* __restrict__ totE, int* __restrict__ baseE,
    const int* __restrict__ totN, int* __restrict__ baseN,
    const int* __restrict__ totG, int* __restrict__ baseG) {
  __shared__ int sc[512];
  int tid = threadIdx.x;
  scanOne512(totE, NBE, baseE, sc, tid);
  scanOne512(totN, NBN, baseN, sc, tid);
  scanOne512(totG, NBG, baseG, sc, tid);
}

// ---------- KP1: bucket partition (packed 8B/4B records) + se atomics ----------
__global__ __launch_bounds__(1024) void KP1_k(
    const int* __restrict__ he_node, const int* __restrict__ he_edge,
    const float* __restrict__ stoich,
    const int* __restrict__ baseE, const int* __restrict__ baseN,
    const int* __restrict__ baseG,
    const int* __restrict__ chE, const int* __restrict__ chN,
    const int* __restrict__ chG,
    int2* __restrict__ scrE, int2* __restrict__ scrN, int* __restrict__ scrG,
    const int* __restrict__ rtg_rxn, const int* __restrict__ rtg_gene,
    const float* __restrict__ gdot0, const float* __restrict__ gdot1,
    float* __restrict__ seAcc0, float* __restrict__ seAcc1) {
  int c = blockIdx.x, tid = threadIdx.x;
  __shared__ int cursE[NBE], cursN[NBN], cursG[NBG];
  if (tid < NBE) cursE[tid] = baseE[tid] + chE[c * NBE + tid];
  if (tid < NBN) cursN[tid] = baseN[tid] + chN[c * NBN + tid];
  if (c < NCHG && tid < NBG) cursG[tid] = baseG[tid] + chG[c * NBG + tid];
  __syncthreads();
  int i = c * 1024 + tid;
  int n = he_node[i], e = he_edge[i];
  int st = __float_as_int(stoich[i]);
  int dE = atomicAdd(&cursE[e >> 4], 1);
  scrE[dE] = make_int2((e << 12) | n, st);
  int dN = atomicAdd(&cursN[n >> 3], 1);
  scrN[dN] = make_int2((n << 13) | e, st);
  if (c < NCHG) {
    int r = rtg_rxn[i], g = rtg_gene[i];
    int dG = atomicAdd(&cursG[g >> 4], 1);
    scrG[dG] = (g << 13) | r;
    atomicAdd(&seAcc0[r], gdot0[g]);
    atomicAdd(&seAcc1[r], gdot1[g]);
  }
}

// ---------- GEMM body: Y(half,scaled) = X @ W; optional renorm; fused sn(f32) ----------
template <bool RENORM, bool XH>
__device__ __forceinline__ void gemm_body(const void* __restrict__ Xv,
                                          const float* __restrict__ W,
                                          const float* __restrict__ att,
                                          __half* __restrict__ Y,
                                          float* __restrict__ sn, int M, int r0) {
  __shared__ float Xs[256][20];
  __shared__ float red[4][16];
  __shared__ float scl[16];
  int tid = threadIdx.x;
  int w = tid >> 6, lane = tid & 63;
  float xv[16];
  #pragma unroll
  for (int i = 0; i < 16; ++i) {
    int r = r0 + i;
    if (r < M) {
      if (XH) xv[i] = __half2float(((const __half*)Xv)[(size_t)r * DD + tid]);
      else    xv[i] = ((const float*)Xv)[(size_t)r * DD + tid];
    } else xv[i] = 0.f;
  }
  if (RENORM) {
    #pragma unroll
    for (int i = 0; i < 16; ++i) {
      float v = waveSum(xv[i] * xv[i]);
      if (lane == 0) red[w][i] = v;
    }
    __syncthreads();
    if (tid < 16) {
      float t = red[0][tid] + red[1][tid] + red[2][tid] + red[3][tid];
      scl[tid] = fminf(1.f, 1.f / (sqrtf(t) + 1e-12f));
    }
    __syncthreads();
    #pragma unroll
    for (int i = 0; i < 16; ++i) xv[i] *= scl[i];
  }
  #pragma unroll
  for (int i = 0; i < 16; ++i) Xs[tid][i] = xv[i];
  __syncthreads();
  float acc[16];
  #pragma unroll
  for (int i = 0; i < 16; ++i) acc[i] = 0.f;
  const float* wp = W + tid;
  #pragma unroll 8
  for (int k = 0; k < 256; ++k) {
    float wv = wp[(size_t)k * DD];
    const float4* xr = reinterpret_cast<const float4*>(&Xs[k][0]);
    float4 a0 = xr[0], a1 = xr[1], a2 = xr[2], a3 = xr[3];
    acc[0]  += a0.x * wv; acc[1]  += a0.y * wv; acc[2]  += a0.z * wv; acc[3]  += a0.w * wv;
    acc[4]  += a1.x * wv; acc[5]  += a1.y * wv; acc[6]  += a1.z * wv; acc[7]  += a1.w * wv;
    acc[8]  += a2.x * wv; acc[9]  += a2.y * wv; acc[10] += a2.z * wv; acc[11] += a2.w * wv;
    acc[12] += a3.x * wv; acc[13] += a3.y * wv; acc[14] += a3.z * wv; acc[15] += a3.w * wv;
  }
  const float ysc = XH ? 1.f : SCL;
  #pragma unroll
  for (int i = 0; i < 16; ++i) {
    int r = r0 + i;
    if (r < M) Y[(size_t)r * DD + tid] = __float2half_rn(acc[i] * ysc);
  }
  float av = att[tid];
  __syncthreads();
  #pragma unroll
  for (int i = 0; i < 16; ++i) {
    float v = waveSum(acc[i] * av);
    if (lane == 0) red[w][i] = v;
  }
  __syncthreads();
  if (tid < 16) {
    int r = r0 + tid;
    if (r < M) sn[r] = (red[0][tid] + red[1][tid] + red[2][tid] + red[3][tid])
                       * (XH ? SCLI : 1.f);
  }
}

// ---------- KP2: in-bucket count+scan → offs + placement (fine buckets) + gemm0 ----------
__global__ __launch_bounds__(256) void KP2_k(
    const int* __restrict__ baseE, const int* __restrict__ baseN,
    const int* __restrict__ baseG,
    const int2* __restrict__ scrE, const int2* __restrict__ scrN,
    const int* __restrict__ scrG,
    int* __restrict__ offsE, int* __restrict__ offsN, int* __restrict__ offsG,
    int2* __restrict__ payE, int2* __restrict__ payN, int* __restrict__ rxnG,
    const float* __restrict__ emb, const float* __restrict__ W0,
    const float* __restrict__ att0, __half* __restrict__ xp,
    float* __restrict__ sn) {
  int blk = blockIdx.x, tid = threadIdx.x;
  if (blk >= KP2_GEMM0) {
    gemm_body<true, false>(emb, W0, att0, xp, sn, N_MET, (blk - KP2_GEMM0) * 16);
    return;
  }
  __shared__ int cnt[16];
  __shared__ int curs[16];
  int side, b, klo, keys, kcnt, nk;
  const int* base;
  if (blk < NBE)            { side = 0; b = blk;             base = baseE; keys = 16; klo = 16 * b; nk = N_RXN;  }
  else if (blk < NBE + NBN) { side = 1; b = blk - NBE;       base = baseN; keys = 8;  klo = 8 * b;  nk = N_MET;  }
  else                      { side = 2; b = blk - NBE - NBN; base = baseG; keys = 16; klo = 16 * b; nk = N_GENE; }
  kcnt = nk - klo; if (kcnt > keys) kcnt = keys;
  int lo = base[b], hi = base[b + 1];
  if (tid < 16) cnt[tid] = 0;
  __syncthreads();
  // count pass
  for (int j = lo + tid; j < hi; j += 256) {
    int key;
    if (side == 0)      key = (scrE[j].x >> 12) - klo;
    else if (side == 1) key = (scrN[j].x >> 13) - klo;
    else                key = (scrG[j]   >> 13) - klo;
    atomicAdd(&cnt[key], 1);
  }
  __syncthreads();
  // wave-0 scan over <=16 counters + offs write
  if (tid < 16) {
    int v = (tid < keys) ? cnt[tid] : 0;
    int inc = v;
    #pragma unroll
    for (int o = 1; o < 16; o <<= 1) { int t = __shfl_up(inc, o, 64); if (tid >= o) inc += t; }
    int ex = inc - v;
    curs[tid] = lo + ex;
    int* offs = (side == 0) ? offsE : (side == 1) ? offsN : offsG;
    if (tid < kcnt) offs[klo + tid] = lo + ex;
    if (tid == 0 && klo + kcnt == nk) offs[nk] = hi;
  }
  __syncthreads();
  // place pass
  for (int j = lo + tid; j < hi; j += 256) {
    if (side == 0) {
      int2 r = scrE[j];
      int e = r.x >> 12, n = r.x & 4095;
      int slot = atomicAdd(&curs[e - klo], 1);
      payE[slot] = make_int2(n, r.y);
    } else if (side == 1) {
      int2 r = scrN[j];
      int n = r.x >> 13, e = r.x & 8191;
      int slot = atomicAdd(&curs[n - klo], 1);
      payN[slot] = make_int2(e, r.y);
    } else {
      int pw = scrG[j];
      int g = pw >> 13, rr = pw & 8191;
      int slot = atomicAdd(&curs[g - klo], 1);
      rxnG[slot] = rr;
    }
  }
}

// standalone gemm (layer 1): X = cur (half, scaled)
__global__ __launch_bounds__(256) void gemm1_k(const __half* __restrict__ X,
                                               const float* __restrict__ W,
                                               const float* __restrict__ att,
                                               __half* __restrict__ Y,
                                               float* __restrict__ sn, int M) {
  gemm_body<false, true>(X, W, att, Y, sn, M, blockIdx.x * 16);
}

// ---------- 16-deep weighted gather-accumulate over fp16 rows (readlane bcast) ----------
__device__ __forceinline__ void gatherAccH(float4& acc, const uint2* __restrict__ src,
                                           const int (&rv)[4], const float (&wv)[4],
                                           int nc, int lane) {
  #pragma unroll
  for (int c = 0; c < 4; ++c) {
    int lim = nc - c * 64; if (lim > 64) lim = 64;
    for (int t = 0; t < lim; t += 16) {
      uint2 a[16]; float w[16];
      #pragma unroll
      for (int q = 0; q < 16; ++q) {
        int   n = bcasti(rv[c], t + q);
        w[q]    = bcastf(wv[c], t + q);
        a[q]    = src[(size_t)n * 64 + lane];
      }
      #pragma unroll
      for (int q = 0; q < 16; ++q) {
        float4 f = h4f(a[q]);
        acc.x += w[q] * f.x; acc.y += w[q] * f.y;
        acc.z += w[q] * f.z; acc.w += w[q] * f.w;
      }
    }
  }
}

// ---------- segment mean (wave per segment), fp16 rows ----------
template <int STRIDE, bool F32OUT>
__global__ __launch_bounds__(256) void seg_mean_k(const int* __restrict__ offs,
                                                  const int* __restrict__ pay,
                                                  const uint2* __restrict__ src,
                                                  void* __restrict__ dst, int nseg) {
  int wid = (blockIdx.x * 256 + threadIdx.x) >> 6;
  int lane = threadIdx.x & 63;
  if (wid >= nseg) return;
  int beg = offs[wid], end = offs[wid + 1];
  int cnt = end - beg;
  int nc = cnt < 256 ? cnt : 256;
  int rv[4]; float wv[4];
  #pragma unroll
  for (int c = 0; c < 4; ++c) {
    int j = c * 64 + lane;
    if (j < nc) { rv[c] = pay[(size_t)(beg + j) * STRIDE]; wv[c] = 1.f; }
    else        { rv[c] = 0;                               wv[c] = 0.f; }
  }
  float4 acc = make_float4(0.f, 0.f, 0.f, 0.f);
  gatherAccH(acc, src, rv, wv, nc, lane);
  for (int j = 256; j < cnt; ++j) {
    int n = pay[(size_t)(beg + j) * STRIDE];
    float4 a = h4f(src[(size_t)n * 64 + lane]);
    acc.x += a.x; acc.y += a.y; acc.z += a.z; acc.w += a.w;
  }
  float inv = 1.f / (float)(cnt > 1 ? cnt : 1);
  float4 o; o.x = acc.x * inv; o.y = acc.y * inv; o.z = acc.z * inv; o.w = acc.w * inv;
  if (F32OUT) {
    o.x *= SCLI; o.y *= SCLI; o.z *= SCLI; o.w *= SCLI;
    ((float4*)dst)[(size_t)wid * 64 + lane] = o;
  } else {
    ((uint2*)dst)[(size_t)wid * 64 + lane] = f4h(o);
  }
}

// ---------- me: wave per reaction; softmax (f32) + fp16-row gather ----------
__global__ __launch_bounds__(256) void me_k(const int* __restrict__ offs,
                                            const int2* __restrict__ payE,
                                            const float* __restrict__ sn,
                                            const float* __restrict__ seAcc,
                                            const int* __restrict__ cntR,
                                            const uint2* __restrict__ xp,
                                            uint2* __restrict__ me,
                                            float4* __restrict__ rstat) {
  int wid = (blockIdx.x * 256 + threadIdx.x) >> 6;
  int lane = threadIdx.x & 63;
  if (wid >= N_RXN) return;
  int rc = cntR[wid];
  float ser = seAcc[wid] / (float)(rc > 1 ? rc : 1);

  int beg = offs[wid], end = offs[wid + 1];
  int cnt = end - beg;
  int nc = cnt < 256 ? cnt : 256;
  int nv[4]; float wv[4]; float stv[4];
  float lmax = -1e30f;
  #pragma unroll
  for (int c = 0; c < 4; ++c) {
    int j = c * 64 + lane;
    if (j < nc) {
      int2 p = payE[beg + j];
      float l = sn[p.x] + ser;
      l = (l >= 0.f) ? l : 0.2f * l;
      nv[c] = p.x; wv[c] = l; stv[c] = __int_as_float(p.y);
      lmax = fmaxf(lmax, l);
    } else { nv[c] = 0; wv[c] = -1e30f; stv[c] = 0.f; }
  }
  for (int j = 256 + lane; j < cnt; j += 64) {
    int2 p = payE[beg + j];
    float l = sn[p.x] + ser;
    l = (l >= 0.f) ? l : 0.2f * l;
    lmax = fmaxf(lmax, l);
  }
  float m = waveMax(lmax);
  float s = 0.f;
  #pragma unroll
  for (int c = 0; c < 4; ++c) {
    if (c * 64 + lane < nc) { float e = expf(wv[c] - m); wv[c] = e; s += e; }
    else wv[c] = 0.f;
  }
  for (int j = 256 + lane; j < cnt; j += 64) {
    int2 p = payE[beg + j];
    float l = sn[p.x] + ser;
    l = (l >= 0.f) ? l : 0.2f * l;
    s += expf(l - m);
  }
  s = waveSum(s);
  float invS = 1.f / (s + 1e-16f);
  #pragma unroll
  for (int c = 0; c < 4; ++c) {
    if (c * 64 + lane < nc) wv[c] = stv[c] * wv[c] * invS;
  }
  if (lane == 0) rstat[wid] = make_float4(ser, m, invS, 0.f);
  float4 acc = make_float4(0.f, 0.f, 0.f, 0.f);
  gatherAccH(acc, xp, nv, wv, nc, lane);
  for (int j = 256; j < cnt; ++j) {
    int2 p = payE[beg + j];
    float l = sn[p.x] + ser;
    l = (l >= 0.f) ? l : 0.2f * l;
    float w = __int_as_float(p.y) * expf(l - m) * invS;
    float4 a = h4f(xp[(size_t)p.x * 64 + lane]);
    acc.x += w * a.x; acc.y += w * a.y; acc.z += w * a.z; acc.w += w * a.w;
  }
  float invB = 1.f / (float)(cnt > 1 ? cnt : 1);
  float4 o; o.x = acc.x * invB; o.y = acc.y * invB; o.z = acc.z * invB; o.w = acc.w * invB;
  me[(size_t)wid * 64 + lane] = f4h(o);   // stays scaled by SCL
}

// ---------- out: wave per metabolite; fp16-row gather + tanh (+ skip + LN) ----------
template <bool LN>
__global__ __launch_bounds__(256) void out_k(const int* __restrict__ offs,
                                             const int2* __restrict__ payN,
                                             const float* __restrict__ sn,
                                             const float4* __restrict__ rstat,
                                             const uint2* __restrict__ me,
                                             const float* __restrict__ bias,
                                             const float* __restrict__ ln_g,
                                             const float* __restrict__ ln_b,
                                             uint2* __restrict__ cur) {
  int wid = (blockIdx.x * 256 + threadIdx.x) >> 6;
  int lane = threadIdx.x & 63;
  if (wid >= N_MET) return;
  int beg = offs[wid], end = offs[wid + 1];
  int cnt = end - beg;
  int nc = cnt < 256 ? cnt : 256;
  float sn_n = sn[wid];
  int rv[4]; float wv[4];
  #pragma unroll
  for (int c = 0; c < 4; ++c) {
    int j = c * 64 + lane;
    if (j < nc) {
      int2 p = payN[beg + j];
      float4 st = rstat[p.x];
      float l = sn_n + st.x;
      l = (l >= 0.f) ? l : 0.2f * l;
      rv[c] = p.x;
      wv[c] = __int_as_float(p.y) * expf(l - st.y) * st.z;
    } else { rv[c] = 0; wv[c] = 0.f; }
  }
  float4 acc = make_float4(0.f, 0.f, 0.f, 0.f);
  gatherAccH(acc, me, rv, wv, nc, lane);
  for (int j = 256; j < cnt; ++j) {
    int2 p = payN[beg + j];
    float4 st = rstat[p.x];
    float l = sn_n + st.x;
    l = (l >= 0.f) ? l : 0.2f * l;
    float w = __int_as_float(p.y) * expf(l - st.y) * st.z;
    float4 a = h4f(me[(size_t)p.x * 64 + lane]);
    acc.x += w * a.x; acc.y += w * a.y; acc.z += w * a.z; acc.w += w * a.w;
  }
  float invD = SCLI / (float)(cnt > 1 ? cnt : 1);   // unscale + mean
  float4 b4 = ((const float4*)bias)[lane];
  float4 o;                                          // unscaled f32 tanh output
  o.x = tanhf(acc.x * invD + b4.x);
  o.y = tanhf(acc.y * invD + b4.y);
  o.z = tanhf(acc.z * invD + b4.z);
  o.w = tanhf(acc.w * invD + b4.w);
  if (!LN) {
    float4 so; so.x = o.x * SCL; so.y = o.y * SCL; so.z = o.z * SCL; so.w = o.w * SCL;
    cur[(size_t)wid * 64 + lane] = f4h(so);
    return;
  }
  float4 p = h4f(cur[(size_t)wid * 64 + lane]);
  p.x *= SCLI; p.y *= SCLI; p.z *= SCLI; p.w *= SCLI;   // unscale skip
  float4 z; z.x = o.x + p.x; z.y = o.y + p.y; z.z = o.z + p.z; z.w = o.w + p.w;
  float mu = waveSum(z.x + z.y + z.z + z.w) * (1.f / 256.f);
  float4 zc; zc.x = z.x - mu; zc.y = z.y - mu; zc.z = z.z - mu; zc.w = z.w - mu;
  float var = waveSum(zc.x * zc.x + zc.y * zc.y + zc.z * zc.z + zc.w * zc.w) * (1.f / 256.f);
  float rs = 1.f / sqrtf(var + 1e-5f);
  float4 g4 = ((const float4*)ln_g)[lane];
  float4 be4 = ((const float4*)ln_b)[lane];
  float4 r;
  r.x = (zc.x * rs * g4.x + be4.x) * SCL;
  r.y = (zc.y * rs * g4.y + be4.y) * SCL;
  r.z = (zc.z * rs * g4.z + be4.z) * SCL;
  r.w = (zc.w * rs * g4.w + be4.w) * SCL;
  cur[(size_t)wid * 64 + lane] = f4h(r);
}

// ---------- launcher ----------
extern "C" void kernel_launch(void* const* d_in, const int* in_sizes, int n_in,
                              void* d_out, int out_size, void* d_ws, size_t ws_size,
                              hipStream_t stream) {
  const int*   he_node = (const int*)d_in[0];
  const int*   he_edge = (const int*)d_in[1];
  const float* stoich  = (const float*)d_in[2];
  const float* gene_x  = (const float*)d_in[3];
  const int*   rtg_rxn = (const int*)d_in[4];
  const int*   rtg_gene= (const int*)d_in[5];
  const float* emb     = (const float*)d_in[6];
  const float* W0      = (const float*)d_in[7];
  const float* We0     = (const float*)d_in[8];
  const float* att0    = (const float*)d_in[9];
  const float* b0      = (const float*)d_in[10];
  const float* W1      = (const float*)d_in[11];
  const float* We1     = (const float*)d_in[12];
  const float* att1    = (const float*)d_in[13];
  const float* b1      = (const float*)d_in[14];
  const float* ln_g    = (const float*)d_in[15];
  const float* ln_b    = (const float*)d_in[16];
  float* out = (float*)d_out;

  char* base = (char*)d_ws;
  size_t off = 0;
  auto carve = [&](size_t bytes) -> char* {
    char* p = base + off;
    off += (bytes + 255) & ~(size_t)255;
    return p;
  };
  __half* xp_h   = (__half*)carve((size_t)N_MET * DD * 2);
  __half* me_h   = (__half*)carve((size_t)N_RXN * DD * 2);
  __half* cur_h  = (__half*)carve((size_t)N_MET * DD * 2);
  __half* rxnf_h = (__half*)carve((size_t)N_RXN * DD * 2);
  float*  sn    = (float*)carve((size_t)N_MET * 4);
  float*  ve0   = (float*)carve(DD * 4);
  float*  ve1   = (float*)carve(DD * 4);
  float*  gdot0 = (float*)carve((size_t)N_GENE * 4);
  float*  gdot1 = (float*)carve((size_t)N_GENE * 4);
  float4* rstat = (float4*)carve((size_t)N_RXN * 16);
  // zeroed region: cntR + seAcc0 + seAcc1
  int ztot = 3 * N_RXN;
  int* zbase = (int*)carve((size_t)ztot * 4);
  int*   cntR   = zbase;
  float* seAcc0 = (float*)(cntR + N_RXN);
  float* seAcc1 = seAcc0 + N_RXN;
  int*  offsE = (int*)carve((N_RXN + 1) * 4);
  int2* payE  = (int2*)carve((size_t)NE * 8);
  int*  offsN = (int*)carve((N_MET + 1) * 4);
  int2* payN  = (int2*)carve((size_t)NE * 8);
  int*  offsG = (int*)carve((N_GENE + 1) * 4);
  int*  rxnG  = (int*)carve((size_t)NP * 4);
  int2* scrE  = (int2*)carve((size_t)NE * 8);
  int2* scrN  = (int2*)carve((size_t)NE * 8);
  int*  scrG  = (int*)carve((size_t)NP * 4);
  int*  chE   = (int*)carve((size_t)NCHUNK * NBE * 4);
  int*  chN   = (int*)carve((size_t)NCHUNK * NBN * 4);
  int*  chG   = (int*)carve((size_t)NCHG * NBG * 4);
  int*  totE  = (int*)carve((NBE + 1) * 4);
  int*  totN  = (int*)carve((NBN + 1) * 4);
  int*  totG  = (int*)carve((NBG + 1) * 4);
  int*  baseE = (int*)carve((NBE + 1) * 4);
  int*  baseN = (int*)carve((NBN + 1) * 4);
  int*  baseG = (int*)carve((NBG + 1) * 4);

  hipMemsetAsync(zbase, 0, (size_t)ztot * 4, stream);

  // KH: vedot + LDS bucket hists (+ cntR atomics)
  KH_k<<<32 + NCHUNK, 1024, 0, stream>>>(
      he_node, he_edge, rtg_rxn, rtg_gene, cntR,
      chE, chN, chG, We0, att0, We1, att1, ve0, ve1);

  // KScan: column scans (emit per-bucket totals) + gdot
  int gdot_blocks = (N_GENE + 15) / 16;
  KScan_k<<<65 + gdot_blocks, 1024, 0, stream>>>(
      chE, chN, chG, totE, totN, totG, gene_x, ve0, ve1, gdot0, gdot1);

  // KBase: bucket-total exclusive scans -> base arrays
  KBase_k<<<1, 512, 0, stream>>>(totE, baseE, totN, baseN, totG, baseG);

  // KP1: bucket partition (packed records, LDS cursors from bases) + se atomics
  KP1_k<<<NCHUNK, 1024, 0, stream>>>(
      he_node, he_edge, stoich, baseE, baseN, baseG, chE, chN, chG,
      scrE, scrN, scrG, rtg_rxn, rtg_gene, gdot0, gdot1, seAcc0, seAcc1);

  // KP2: fine-bucket count/scan -> offs + placement + gemm0 (xp fp16)
  KP2_k<<<KP2_GEMM0 + GEMM_BLOCKS, 256, 0, stream>>>(
      baseE, baseN, baseG, scrE, scrN, scrG,
      offsE, offsN, offsG, payE, payN, rxnG,
      emb, W0, att0, xp_h, sn);

  // layer 0
  me_k<<<(N_RXN + 3) / 4, 256, 0, stream>>>(offsE, payE, sn, seAcc0, cntR,
                                            (const uint2*)xp_h, (uint2*)me_h, rstat);
  out_k<false><<<(N_MET + 3) / 4, 256, 0, stream>>>(offsN, payN, sn, rstat,
                                                    (const uint2*)me_h, b0,
                                                    nullptr, nullptr, (uint2*)cur_h);

  // layer 1
  gemm1_k<<<GEMM_BLOCKS, 256, 0, stream>>>(cur_h, W1, att1, xp_h, sn, N_MET);
  me_k<<<(N_RXN + 3) / 4, 256, 0, stream>>>(offsE, payE, sn, seAcc1, cntR,
                                            (const uint2*)xp_h, (uint2*)me_h, rstat);
  out_k<true><<<(N_MET + 3) / 4, 256, 0, stream>>>(offsN, payN, sn, rstat,
                                                   (const uint2*)me_h, b1,
                                                   ln_g, ln_b, (uint2*)cur_h);

  // final readout
  seg_mean_k<2, false><<<(N_RXN + 3) / 4, 256, 0, stream>>>(
      offsE, (const int*)payE, (const uint2*)cur_h, rxnf_h, N_RXN);
  seg_mean_k<1, true><<<(N_GENE + 3) / 4, 256, 0, stream>>>(
      offsG, rxnG, (const uint2*)rxnf_h, out, N_GENE);
}

// Round 14
// 197.640 us; speedup vs baseline: 1.1179x; 1.0268x over previous
//
#include <hip/hip_runtime.h>
#include <hip/hip_fp16.h>
#include <math.h>

#define DD 256
static constexpr int N_MET  = 2534;
static constexpr int N_RXN  = 4881;
static constexpr int N_GENE = 6607;
static constexpr int NE     = 262144;
static constexpr int NP     = 131072;

static constexpr int NCHUNK = 256;       // NE / 1024
static constexpr int NCHG   = 128;       // NP / 1024
static constexpr int NBE    = 77;        // edge buckets of 64
static constexpr int NBN    = 80;        // node buckets of 32
static constexpr int NBG    = 104;       // gene buckets of 64
static constexpr int CHS    = 80;        // chE/chN stride
static constexpr int NCOL   = NBE + NBN + NBG;          // 261 scan columns
static constexpr int GEMM_BLOCKS = (N_MET + 15) / 16;   // 159
static constexpr int KP2_GEMM0 = NBE + NBN + NBG;       // 261

static constexpr float SCL  = 2048.f;    // fp16 storage scale (linear pipeline)
static constexpr float SCLI = 1.f / 2048.f;

// ---------- wave reductions / broadcasts (64 lanes) ----------
__device__ __forceinline__ float waveSum(float v) {
  #pragma unroll
  for (int o = 32; o > 0; o >>= 1) v += __shfl_xor(v, o, 64);
  return v;
}
__device__ __forceinline__ float waveMax(float v) {
  #pragma unroll
  for (int o = 32; o > 0; o >>= 1) v = fmaxf(v, __shfl_xor(v, o, 64));
  return v;
}
__device__ __forceinline__ int   bcasti(int v, int l)   { return __builtin_amdgcn_readlane(v, l); }
__device__ __forceinline__ float bcastf(float v, int l) {
  return __int_as_float(__builtin_amdgcn_readlane(__float_as_int(v), l));
}

// ---------- fp16x4 <-> f32x4 ----------
__device__ __forceinline__ float4 h4f(uint2 u) {
  __half2 a = *reinterpret_cast<__half2*>(&u.x);
  __half2 b = *reinterpret_cast<__half2*>(&u.y);
  float2 fa = __half22float2(a), fb = __half22float2(b);
  return make_float4(fa.x, fa.y, fb.x, fb.y);
}
__device__ __forceinline__ uint2 f4h(float4 v) {
  __half2 a = __floats2half2_rn(v.x, v.y);
  __half2 b = __floats2half2_rn(v.z, v.w);
  uint2 u;
  u.x = *reinterpret_cast<unsigned*>(&a);
  u.y = *reinterpret_cast<unsigned*>(&b);
  return u;
}

// ---------- KH: vedot (blk 0..31) + LDS bucket hists + cntR (blk 32..287) ----------
__global__ __launch_bounds__(1024) void KH_k(
    const int* __restrict__ he_node, const int* __restrict__ he_edge,
    const int* __restrict__ rtg_rxn, const int* __restrict__ rtg_gene,
    int* cntR,
    int* __restrict__ chE, int* __restrict__ chN, int* __restrict__ chG,
    const float* __restrict__ We0, const float* __restrict__ att0,
    const float* __restrict__ We1, const float* __restrict__ att1,
    float* __restrict__ ve0, float* __restrict__ ve1) {
  int blk = blockIdx.x, tid = threadIdx.x;
  if (blk < 32) {
    int wid = blk * 16 + (tid >> 6);   // 0..511
    int lane = tid & 63;
    const float* We = (wid < 256) ? We0 : We1;
    const float* at = (wid < 256) ? att0 : att1;
    int r = wid & 255;
    float4 a = ((const float4*)(We + (size_t)r * DD))[lane];
    float4 v = ((const float4*)(at + DD))[lane];
    float s = waveSum(a.x * v.x + a.y * v.y + a.z * v.z + a.w * v.w);
    if (lane == 0) ((wid < 256) ? ve0 : ve1)[r] = s;
    return;
  }
  int c = blk - 32;                     // chunk id, 0..255
  __shared__ int hE[NBE], hN[NBN], hG[NBG];
  if (tid < NBE) hE[tid] = 0;
  if (tid >= 128 && tid < 128 + NBN) hN[tid - 128] = 0;
  if (tid >= 256 && tid < 256 + NBG) hG[tid - 256] = 0;
  __syncthreads();
  int i = c * 1024 + tid;               // i < NE always
  int n = he_node[i], e = he_edge[i];
  atomicAdd(&hE[e >> 6], 1); atomicAdd(&hN[n >> 5], 1);
  if (c < NCHG) {
    int r = rtg_rxn[i], g = rtg_gene[i];
    atomicAdd(&cntR[r], 1);
    atomicAdd(&hG[g >> 6], 1);
  }
  __syncthreads();
  if (tid < NBE) chE[c * CHS + tid] = hE[tid];
  if (tid >= 128 && tid < 128 + NBN) chN[c * CHS + (tid - 128)] = hN[tid - 128];
  if (c < NCHG && tid >= 256 && tid < 256 + NBG) chG[c * NBG + (tid - 256)] = hG[tid - 256];
}

// ---------- KScan: column scans (blk 0..16, emit bucket totals) + gdot ----------
__global__ __launch_bounds__(1024) void KScan_k(
    int* __restrict__ chE, int* __restrict__ chN, int* __restrict__ chG,
    int* __restrict__ totE, int* __restrict__ totN, int* __restrict__ totG,
    const float* __restrict__ gene_x,
    const float* __restrict__ ve0, const float* __restrict__ ve1,
    float* __restrict__ gdot0, float* __restrict__ gdot1) {
  int blk = blockIdx.x, tid = threadIdx.x;
  if (blk < 17) {
    int colw = blk * 16 + (tid >> 6);
    int lane = tid & 63;
    if (colw >= NCOL) return;
    if (colw < NBE + NBN) {
      int side = colw >= NBE;
      int b = colw - side * NBE;
      int* ch = side ? chN : chE;
      int* tot = side ? totN : totE;
      int v[4]; int s = 0;
      int cbase = lane * 4;
      #pragma unroll
      for (int k = 0; k < 4; ++k) { v[k] = ch[(cbase + k) * CHS + b]; s += v[k]; }
      int inc = s;
      #pragma unroll
      for (int o = 1; o < 64; o <<= 1) { int t = __shfl_up(inc, o, 64); if (lane >= o) inc += t; }
      if (lane == 63) tot[b] = inc;
      int ex = inc - s;
      #pragma unroll
      for (int k = 0; k < 4; ++k) { int t = v[k]; ch[(cbase + k) * CHS + b] = ex; ex += t; }
    } else {
      int b = colw - NBE - NBN;
      int v[2]; int s = 0;
      int cbase = lane * 2;
      #pragma unroll
      for (int k = 0; k < 2; ++k) { v[k] = chG[(cbase + k) * NBG + b]; s += v[k]; }
      int inc = s;
      #pragma unroll
      for (int o = 1; o < 64; o <<= 1) { int t = __shfl_up(inc, o, 64); if (lane >= o) inc += t; }
      if (lane == 63) totG[b] = inc;
      int ex = inc - s;
      #pragma unroll
      for (int k = 0; k < 2; ++k) { int t = v[k]; chG[(cbase + k) * NBG + b] = ex; ex += t; }
    }
    return;
  }
  // gdot
  int wid = (blk - 17) * 16 + (tid >> 6);
  int lane = tid & 63;
  if (wid >= N_GENE) return;
  float4 a  = ((const float4*)gene_x)[(size_t)wid * 64 + lane];
  float4 v0 = ((const float4*)ve0)[lane];
  float4 v1 = ((const float4*)ve1)[lane];
  float s0 = waveSum(a.x * v0.x + a.y * v0.y + a.z * v0.z + a.w * v0.w);
  float s1 = waveSum(a.x * v1.x + a.y * v1.y + a.z * v1.z + a.w * v1.w);
  if (lane == 0) { gdot0[wid] = s0; gdot1[wid] = s1; }
}

// in-place 128-entry LDS inclusive scan
__device__ __forceinline__ void ldsScan128(int* sc, int tid) {
  #pragma unroll
  for (int o = 1; o < 128; o <<= 1) {
    int t = (tid < 128 && tid >= o) ? sc[tid - o] : 0;
    __syncthreads();
    if (tid < 128) sc[tid] += t;
    __syncthreads();
  }
}

// ---------- KP1: bucket partition (packed 8B/4B records) + se atomics ----------
__global__ __launch_bounds__(1024) void KP1_k(
    const int* __restrict__ he_node, const int* __restrict__ he_edge,
    const float* __restrict__ stoich,
    const int* __restrict__ chE, const int* __restrict__ chN,
    const int* __restrict__ chG,
    const int* __restrict__ totE, const int* __restrict__ totN,
    const int* __restrict__ totG,
    int2* __restrict__ scrE, int2* __restrict__ scrN, int* __restrict__ scrG,
    const int* __restrict__ rtg_rxn, const int* __restrict__ rtg_gene,
    const float* __restrict__ gdot0, const float* __restrict__ gdot1,
    float* __restrict__ seAcc0, float* __restrict__ seAcc1) {
  int c = blockIdx.x, tid = threadIdx.x;
  __shared__ int sc[128];
  __shared__ int cursE[NBE], cursN[NBN], cursG[NBG];
  int v;
  if (tid < 128) sc[tid] = (tid < NBE) ? totE[tid] : 0;
  if (tid < 128) v = sc[tid];
  __syncthreads();
  ldsScan128(sc, tid);
  if (tid < NBE) cursE[tid] = (sc[tid] - v) + chE[c * CHS + tid];
  __syncthreads();
  if (tid < 128) sc[tid] = (tid < NBN) ? totN[tid] : 0;
  if (tid < 128) v = sc[tid];
  __syncthreads();
  ldsScan128(sc, tid);
  if (tid < NBN) cursN[tid] = (sc[tid] - v) + chN[c * CHS + tid];
  __syncthreads();
  if (c < NCHG) {
    if (tid < 128) sc[tid] = (tid < NBG) ? totG[tid] : 0;
    if (tid < 128) v = sc[tid];
    __syncthreads();
    ldsScan128(sc, tid);
    if (tid < NBG) cursG[tid] = (sc[tid] - v) + chG[c * NBG + tid];
  }
  __syncthreads();
  int i = c * 1024 + tid;
  int n = he_node[i], e = he_edge[i];
  int st = __float_as_int(stoich[i]);
  int dE = atomicAdd(&cursE[e >> 6], 1);
  scrE[dE] = make_int2((e << 12) | n, st);
  int dN = atomicAdd(&cursN[n >> 5], 1);
  scrN[dN] = make_int2((n << 13) | e, st);
  if (c < NCHG) {
    int r = rtg_rxn[i], g = rtg_gene[i];
    int dG = atomicAdd(&cursG[g >> 6], 1);
    scrG[dG] = (g << 13) | r;
    atomicAdd(&seAcc0[r], gdot0[g]);
    atomicAdd(&seAcc1[r], gdot1[g]);
  }
}

// ---------- GEMM body: Y(half,scaled) = X @ W; optional renorm; fused sn(f32) ----------
// XH=false: X is f32 (unscaled) -> Y = acc*SCL, sn = dot.
// XH=true:  X is half scaled by SCL -> acc already scaled: Y = acc, sn = dot*SCLI.
template <bool RENORM, bool XH>
__device__ __forceinline__ void gemm_body(const void* __restrict__ Xv,
                                          const float* __restrict__ W,
                                          const float* __restrict__ att,
                                          __half* __restrict__ Y,
                                          float* __restrict__ sn, int M, int r0) {
  __shared__ float Xs[256][20];
  __shared__ float red[4][16];
  __shared__ float scl[16];
  int tid = threadIdx.x;
  int w = tid >> 6, lane = tid & 63;
  float xv[16];
  #pragma unroll
  for (int i = 0; i < 16; ++i) {
    int r = r0 + i;
    if (r < M) {
      if (XH) xv[i] = __half2float(((const __half*)Xv)[(size_t)r * DD + tid]);
      else    xv[i] = ((const float*)Xv)[(size_t)r * DD + tid];
    } else xv[i] = 0.f;
  }
  if (RENORM) {
    #pragma unroll
    for (int i = 0; i < 16; ++i) {
      float v = waveSum(xv[i] * xv[i]);
      if (lane == 0) red[w][i] = v;
    }
    __syncthreads();
    if (tid < 16) {
      float t = red[0][tid] + red[1][tid] + red[2][tid] + red[3][tid];
      scl[tid] = fminf(1.f, 1.f / (sqrtf(t) + 1e-12f));
    }
    __syncthreads();
    #pragma unroll
    for (int i = 0; i < 16; ++i) xv[i] *= scl[i];
  }
  #pragma unroll
  for (int i = 0; i < 16; ++i) Xs[tid][i] = xv[i];
  __syncthreads();
  float acc[16];
  #pragma unroll
  for (int i = 0; i < 16; ++i) acc[i] = 0.f;
  const float* wp = W + tid;
  #pragma unroll 8
  for (int k = 0; k < 256; ++k) {
    float wv = wp[(size_t)k * DD];
    const float4* xr = reinterpret_cast<const float4*>(&Xs[k][0]);
    float4 a0 = xr[0], a1 = xr[1], a2 = xr[2], a3 = xr[3];
    acc[0]  += a0.x * wv; acc[1]  += a0.y * wv; acc[2]  += a0.z * wv; acc[3]  += a0.w * wv;
    acc[4]  += a1.x * wv; acc[5]  += a1.y * wv; acc[6]  += a1.z * wv; acc[7]  += a1.w * wv;
    acc[8]  += a2.x * wv; acc[9]  += a2.y * wv; acc[10] += a2.z * wv; acc[11] += a2.w * wv;
    acc[12] += a3.x * wv; acc[13] += a3.y * wv; acc[14] += a3.z * wv; acc[15] += a3.w * wv;
  }
  const float ysc = XH ? 1.f : SCL;
  #pragma unroll
  for (int i = 0; i < 16; ++i) {
    int r = r0 + i;
    if (r < M) Y[(size_t)r * DD + tid] = __float2half_rn(acc[i] * ysc);
  }
  float av = att[tid];
  __syncthreads();
  #pragma unroll
  for (int i = 0; i < 16; ++i) {
    float v = waveSum(acc[i] * av);
    if (lane == 0) red[w][i] = v;
  }
  __syncthreads();
  if (tid < 16) {
    int r = r0 + tid;
    if (r < M) sn[r] = (red[0][tid] + red[1][tid] + red[2][tid] + red[3][tid])
                       * (XH ? SCLI : 1.f);
  }
}

// block-sum over 256 threads (int)
__device__ __forceinline__ int blockSumInt256(int v) {
  __shared__ int s4[4];
  #pragma unroll
  for (int o = 32; o > 0; o >>= 1) v += __shfl_xor(v, o, 64);
  if ((threadIdx.x & 63) == 0) s4[threadIdx.x >> 6] = v;
  __syncthreads();
  return s4[0] + s4[1] + s4[2] + s4[3];
}

// ---------- KP2: in-bucket count+scan → offs + CSR placement + gemm0 ----------
__global__ __launch_bounds__(256) void KP2_k(
    const int* __restrict__ totE, const int* __restrict__ totN,
    const int* __restrict__ totG,
    const int2* __restrict__ scrE, const int2* __restrict__ scrN,
    const int* __restrict__ scrG,
    int* __restrict__ offsE, int* __restrict__ offsN, int* __restrict__ offsG,
    int2* __restrict__ payE, int2* __restrict__ payN, int* __restrict__ rxnG,
    const float* __restrict__ emb, const float* __restrict__ W0,
    const float* __restrict__ att0, __half* __restrict__ xp,
    float* __restrict__ sn) {
  int blk = blockIdx.x, tid = threadIdx.x;
  if (blk >= KP2_GEMM0) {
    gemm_body<true, false>(emb, W0, att0, xp, sn, N_MET, (blk - KP2_GEMM0) * 16);
    return;
  }
  __shared__ int cnt[64];
  __shared__ int curs[64];
  int side, b, klo, kcnt, nk, btot;
  const int* tot;
  if (blk < NBE)            { side = 0; b = blk;             tot = totE; klo = 64 * b; nk = N_RXN;  kcnt = min(64, N_RXN  - klo); }
  else if (blk < NBE + NBN) { side = 1; b = blk - NBE;       tot = totN; klo = 32 * b; nk = N_MET;  kcnt = min(32, N_MET  - klo); }
  else                      { side = 2; b = blk - NBE - NBN; tot = totG; klo = 64 * b; nk = N_GENE; kcnt = min(64, N_GENE - klo); }
  btot = tot[b];
  int pv = (tid < b) ? tot[tid] : 0;
  int base = blockSumInt256(pv);
  if (tid < 64) cnt[tid] = 0;
  __syncthreads();
  int lo = base, hi = base + btot;
  for (int j = lo + tid; j < hi; j += 256) {
    int key;
    if (side == 0)      key = (scrE[j].x >> 12) - klo;
    else if (side == 1) key = (scrN[j].x >> 13) - klo;
    else                key = (scrG[j]   >> 13) - klo;
    atomicAdd(&cnt[key], 1);
  }
  __syncthreads();
  if (tid < 64) {
    int v = cnt[tid];
    int inc = v;
    #pragma unroll
    for (int o = 1; o < 64; o <<= 1) { int t = __shfl_up(inc, o, 64); if (tid >= o) inc += t; }
    int ex = inc - v;
    curs[tid] = base + ex;
    int* offs = (side == 0) ? offsE : (side == 1) ? offsN : offsG;
    if (tid < kcnt) offs[klo + tid] = base + ex;
    if (tid == 0 && klo + kcnt == nk) offs[nk] = base + btot;
  }
  __syncthreads();
  for (int j = lo + tid; j < hi; j += 256) {
    if (side == 0) {
      int2 r = scrE[j];
      int e = r.x >> 12, n = r.x & 4095;
      int slot = atomicAdd(&curs[e - klo], 1);
      payE[slot] = make_int2(n, r.y);
    } else if (side == 1) {
      int2 r = scrN[j];
      int n = r.x >> 13, e = r.x & 8191;
      int slot = atomicAdd(&curs[n - klo], 1);
      payN[slot] = make_int2(e, r.y);
    } else {
      int pw = scrG[j];
      int g = pw >> 13, rr = pw & 8191;
      int slot = atomicAdd(&curs[g - klo], 1);
      rxnG[slot] = rr;
    }
  }
}

// standalone gemm (layer 1): X = cur (half, scaled)
__global__ __launch_bounds__(256) void gemm1_k(const __half* __restrict__ X,
                                               const float* __restrict__ W,
                                               const float* __restrict__ att,
                                               __half* __restrict__ Y,
                                               float* __restrict__ sn, int M) {
  gemm_body<false, true>(X, W, att, Y, sn, M, blockIdx.x * 16);
}

// ---------- 16-deep weighted gather-accumulate over fp16 rows (readlane bcast) ----------
__device__ __forceinline__ void gatherAccH(float4& acc, const uint2* __restrict__ src,
                                           const int (&rv)[4], const float (&wv)[4],
                                           int nc, int lane) {
  #pragma unroll
  for (int c = 0; c < 4; ++c) {
    int lim = nc - c * 64; if (lim > 64) lim = 64;
    for (int t = 0; t < lim; t += 16) {
      uint2 a[16]; float w[16];
      #pragma unroll
      for (int q = 0; q < 16; ++q) {
        int   n = bcasti(rv[c], t + q);
        w[q]    = bcastf(wv[c], t + q);
        a[q]    = src[(size_t)n * 64 + lane];
      }
      #pragma unroll
      for (int q = 0; q < 16; ++q) {
        float4 f = h4f(a[q]);
        acc.x += w[q] * f.x; acc.y += w[q] * f.y;
        acc.z += w[q] * f.z; acc.w += w[q] * f.w;
      }
    }
  }
}

// ---------- segment mean (wave per segment), fp16 rows ----------
// F32OUT: divide by SCL and write f32 (final output); else keep scaled fp16.
template <int STRIDE, bool F32OUT>
__global__ __launch_bounds__(256) void seg_mean_k(const int* __restrict__ offs,
                                                  const int* __restrict__ pay,
                                                  const uint2* __restrict__ src,
                                                  void* __restrict__ dst, int nseg) {
  int wid = (blockIdx.x * 256 + threadIdx.x) >> 6;
  int lane = threadIdx.x & 63;
  if (wid >= nseg) return;
  int beg = offs[wid], end = offs[wid + 1];
  int cnt = end - beg;
  int nc = cnt < 256 ? cnt : 256;
  int rv[4]; float wv[4];
  #pragma unroll
  for (int c = 0; c < 4; ++c) {
    int j = c * 64 + lane;
    if (j < nc) { rv[c] = pay[(size_t)(beg + j) * STRIDE]; wv[c] = 1.f; }
    else        { rv[c] = 0;                               wv[c] = 0.f; }
  }
  float4 acc = make_float4(0.f, 0.f, 0.f, 0.f);
  gatherAccH(acc, src, rv, wv, nc, lane);
  for (int j = 256; j < cnt; ++j) {
    int n = pay[(size_t)(beg + j) * STRIDE];
    float4 a = h4f(src[(size_t)n * 64 + lane]);
    acc.x += a.x; acc.y += a.y; acc.z += a.z; acc.w += a.w;
  }
  float inv = 1.f / (float)(cnt > 1 ? cnt : 1);
  float4 o; o.x = acc.x * inv; o.y = acc.y * inv; o.z = acc.z * inv; o.w = acc.w * inv;
  if (F32OUT) {
    o.x *= SCLI; o.y *= SCLI; o.z *= SCLI; o.w *= SCLI;
    ((float4*)dst)[(size_t)wid * 64 + lane] = o;
  } else {
    ((uint2*)dst)[(size_t)wid * 64 + lane] = f4h(o);
  }
}

// ---------- me: wave per reaction; softmax (f32) + fp16-row gather ----------
__global__ __launch_bounds__(256) void me_k(const int* __restrict__ offs,
                                            const int2* __restrict__ payE,
                                            const float* __restrict__ sn,
                                            const float* __restrict__ seAcc,
                                            const int* __restrict__ cntR,
                                            const uint2* __restrict__ xp,
                                            uint2* __restrict__ me,
                                            float4* __restrict__ rstat) {
  int wid = (blockIdx.x * 256 + threadIdx.x) >> 6;
  int lane = threadIdx.x & 63;
  if (wid >= N_RXN) return;
  int rc = cntR[wid];
  float ser = seAcc[wid] / (float)(rc > 1 ? rc : 1);

  int beg = offs[wid], end = offs[wid + 1];
  int cnt = end - beg;
  int nc = cnt < 256 ? cnt : 256;
  int nv[4]; float wv[4]; float stv[4];
  float lmax = -1e30f;
  #pragma unroll
  for (int c = 0; c < 4; ++c) {
    int j = c * 64 + lane;
    if (j < nc) {
      int2 p = payE[beg + j];
      float l = sn[p.x] + ser;
      l = (l >= 0.f) ? l : 0.2f * l;
      nv[c] = p.x; wv[c] = l; stv[c] = __int_as_float(p.y);
      lmax = fmaxf(lmax, l);
    } else { nv[c] = 0; wv[c] = -1e30f; stv[c] = 0.f; }
  }
  for (int j = 256 + lane; j < cnt; j += 64) {
    int2 p = payE[beg + j];
    float l = sn[p.x] + ser;
    l = (l >= 0.f) ? l : 0.2f * l;
    lmax = fmaxf(lmax, l);
  }
  float m = waveMax(lmax);
  float s = 0.f;
  #pragma unroll
  for (int c = 0; c < 4; ++c) {
    if (c * 64 + lane < nc) { float e = expf(wv[c] - m); wv[c] = e; s += e; }
    else wv[c] = 0.f;
  }
  for (int j = 256 + lane; j < cnt; j += 64) {
    int2 p = payE[beg + j];
    float l = sn[p.x] + ser;
    l = (l >= 0.f) ? l : 0.2f * l;
    s += expf(l - m);
  }
  s = waveSum(s);
  float invS = 1.f / (s + 1e-16f);
  #pragma unroll
  for (int c = 0; c < 4; ++c) {
    if (c * 64 + lane < nc) wv[c] = stv[c] * wv[c] * invS;
  }
  if (lane == 0) rstat[wid] = make_float4(ser, m, invS, 0.f);
  float4 acc = make_float4(0.f, 0.f, 0.f, 0.f);
  gatherAccH(acc, xp, nv, wv, nc, lane);
  for (int j = 256; j < cnt; ++j) {
    int2 p = payE[beg + j];
    float l = sn[p.x] + ser;
    l = (l >= 0.f) ? l : 0.2f * l;
    float w = __int_as_float(p.y) * expf(l - m) * invS;
    float4 a = h4f(xp[(size_t)p.x * 64 + lane]);
    acc.x += w * a.x; acc.y += w * a.y; acc.z += w * a.z; acc.w += w * a.w;
  }
  float invB = 1.f / (float)(cnt > 1 ? cnt : 1);
  float4 o; o.x = acc.x * invB; o.y = acc.y * invB; o.z = acc.z * invB; o.w = acc.w * invB;
  me[(size_t)wid * 64 + lane] = f4h(o);   // stays scaled by SCL
}

// ---------- out: wave per metabolite; fp16-row gather + tanh (+ skip + LN) ----------
template <bool LN>
__global__ __launch_bounds__(256) void out_k(const int* __restrict__ offs,
                                             const int2* __restrict__ payN,
                                             const float* __restrict__ sn,
                                             const float4* __restrict__ rstat,
                                             const uint2* __restrict__ me,
                                             const float* __restrict__ bias,
                                             const float* __restrict__ ln_g,
                                             const float* __restrict__ ln_b,
                                             uint2* __restrict__ cur) {
  int wid = (blockIdx.x * 256 + threadIdx.x) >> 6;
  int lane = threadIdx.x & 63;
  if (wid >= N_MET) return;
  int beg = offs[wid], end = offs[wid + 1];
  int cnt = end - beg;
  int nc = cnt < 256 ? cnt : 256;
  float sn_n = sn[wid];
  int rv[4]; float wv[4];
  #pragma unroll
  for (int c = 0; c < 4; ++c) {
    int j = c * 64 + lane;
    if (j < nc) {
      int2 p = payN[beg + j];
      float4 st = rstat[p.x];
      float l = sn_n + st.x;
      l = (l >= 0.f) ? l : 0.2f * l;
      rv[c] = p.x;
      wv[c] = __int_as_float(p.y) * expf(l - st.y) * st.z;
    } else { rv[c] = 0; wv[c] = 0.f; }
  }
  float4 acc = make_float4(0.f, 0.f, 0.f, 0.f);
  gatherAccH(acc, me, rv, wv, nc, lane);
  for (int j = 256; j < cnt; ++j) {
    int2 p = payN[beg + j];
    float4 st = rstat[p.x];
    float l = sn_n + st.x;
    l = (l >= 0.f) ? l : 0.2f * l;
    float w = __int_as_float(p.y) * expf(l - st.y) * st.z;
    float4 a = h4f(me[(size_t)p.x * 64 + lane]);
    acc.x += w * a.x; acc.y += w * a.y; acc.z += w * a.z; acc.w += w * a.w;
  }
  float invD = SCLI / (float)(cnt > 1 ? cnt : 1);   // unscale + mean
  float4 b4 = ((const float4*)bias)[lane];
  float4 o;                                          // unscaled f32 tanh output
  o.x = tanhf(acc.x * invD + b4.x);
  o.y = tanhf(acc.y * invD + b4.y);
  o.z = tanhf(acc.z * invD + b4.z);
  o.w = tanhf(acc.w * invD + b4.w);
  if (!LN) {
    float4 so; so.x = o.x * SCL; so.y = o.y * SCL; so.z = o.z * SCL; so.w = o.w * SCL;
    cur[(size_t)wid * 64 + lane] = f4h(so);
    return;
  }
  float4 p = h4f(cur[(size_t)wid * 64 + lane]);
  p.x *= SCLI; p.y *= SCLI; p.z *= SCLI; p.w *= SCLI;   // unscale skip
  float4 z; z.x = o.x + p.x; z.y = o.y + p.y; z.z = o.z + p.z; z.w = o.w + p.w;
  float mu = waveSum(z.x + z.y + z.z + z.w) * (1.f / 256.f);
  float4 zc; zc.x = z.x - mu; zc.y = z.y - mu; zc.z = z.z - mu; zc.w = z.w - mu;
  float var = waveSum(zc.x * zc.x + zc.y * zc.y + zc.z * zc.z + zc.w * zc.w) * (1.f / 256.f);
  float rs = 1.f / sqrtf(var + 1e-5f);
  float4 g4 = ((const float4*)ln_g)[lane];
  float4 be4 = ((const float4*)ln_b)[lane];
  float4 r;
  r.x = (zc.x * rs * g4.x + be4.x) * SCL;
  r.y = (zc.y * rs * g4.y + be4.y) * SCL;
  r.z = (zc.z * rs * g4.z + be4.z) * SCL;
  r.w = (zc.w * rs * g4.w + be4.w) * SCL;
  cur[(size_t)wid * 64 + lane] = f4h(r);
}

// ---------- launcher ----------
extern "C" void kernel_launch(void* const* d_in, const int* in_sizes, int n_in,
                              void* d_out, int out_size, void* d_ws, size_t ws_size,
                              hipStream_t stream) {
  const int*   he_node = (const int*)d_in[0];
  const int*   he_edge = (const int*)d_in[1];
  const float* stoich  = (const float*)d_in[2];
  const float* gene_x  = (const float*)d_in[3];
  const int*   rtg_rxn = (const int*)d_in[4];
  const int*   rtg_gene= (const int*)d_in[5];
  const float* emb     = (const float*)d_in[6];
  const float* W0      = (const float*)d_in[7];
  const float* We0     = (const float*)d_in[8];
  const float* att0    = (const float*)d_in[9];
  const float* b0      = (const float*)d_in[10];
  const float* W1      = (const float*)d_in[11];
  const float* We1     = (const float*)d_in[12];
  const float* att1    = (const float*)d_in[13];
  const float* b1      = (const float*)d_in[14];
  const float* ln_g    = (const float*)d_in[15];
  const float* ln_b    = (const float*)d_in[16];
  float* out = (float*)d_out;

  char* base = (char*)d_ws;
  size_t off = 0;
  auto carve = [&](size_t bytes) -> char* {
    char* p = base + off;
    off += (bytes + 255) & ~(size_t)255;
    return p;
  };
  __half* xp_h   = (__half*)carve((size_t)N_MET * DD * 2);
  __half* me_h   = (__half*)carve((size_t)N_RXN * DD * 2);
  __half* cur_h  = (__half*)carve((size_t)N_MET * DD * 2);
  __half* rxnf_h = (__half*)carve((size_t)N_RXN * DD * 2);
  float*  sn    = (float*)carve((size_t)N_MET * 4);
  float*  ve0   = (float*)carve(DD * 4);
  float*  ve1   = (float*)carve(DD * 4);
  float*  gdot0 = (float*)carve((size_t)N_GENE * 4);
  float*  gdot1 = (float*)carve((size_t)N_GENE * 4);
  float4* rstat = (float4*)carve((size_t)N_RXN * 16);
  int ztot = 3 * N_RXN;
  int* zbase = (int*)carve((size_t)ztot * 4);
  int*   cntR   = zbase;
  float* seAcc0 = (float*)(cntR + N_RXN);
  float* seAcc1 = seAcc0 + N_RXN;
  int*  offsE = (int*)carve((N_RXN + 1) * 4);
  int2* payE  = (int2*)carve((size_t)NE * 8);
  int*  offsN = (int*)carve((N_MET + 1) * 4);
  int2* payN  = (int2*)carve((size_t)NE * 8);
  int*  offsG = (int*)carve((N_GENE + 1) * 4);
  int*  rxnG  = (int*)carve((size_t)NP * 4);
  int2* scrE  = (int2*)carve((size_t)NE * 8);
  int2* scrN  = (int2*)carve((size_t)NE * 8);
  int*  scrG  = (int*)carve((size_t)NP * 4);
  int*  chE   = (int*)carve((size_t)NCHUNK * CHS * 4);
  int*  chN   = (int*)carve((size_t)NCHUNK * CHS * 4);
  int*  chG   = (int*)carve((size_t)NCHG * NBG * 4);
  int*  totE  = (int*)carve(128 * 4);
  int*  totN  = (int*)carve(128 * 4);
  int*  totG  = (int*)carve(128 * 4);

  hipMemsetAsync(zbase, 0, (size_t)ztot * 4, stream);

  // KH: vedot + LDS bucket hists (+ cntR atomics)
  KH_k<<<32 + NCHUNK, 1024, 0, stream>>>(
      he_node, he_edge, rtg_rxn, rtg_gene, cntR,
      chE, chN, chG, We0, att0, We1, att1, ve0, ve1);

  // KScan: column scans (emit per-bucket totals) + gdot
  int gdot_blocks = (N_GENE + 15) / 16;
  KScan_k<<<17 + gdot_blocks, 1024, 0, stream>>>(
      chE, chN, chG, totE, totN, totG, gene_x, ve0, ve1, gdot0, gdot1);

  // KP1: bucket partition (packed records, LDS cursors) + se atomics
  KP1_k<<<NCHUNK, 1024, 0, stream>>>(
      he_node, he_edge, stoich, chE, chN, chG, totE, totN, totG,
      scrE, scrN, scrG, rtg_rxn, rtg_gene, gdot0, gdot1, seAcc0, seAcc1);

  // KP2: in-bucket count/scan → offs arrays + CSR placement + gemm0 (xp fp16)
  KP2_k<<<KP2_GEMM0 + GEMM_BLOCKS, 256, 0, stream>>>(
      totE, totN, totG, scrE, scrN, scrG,
      offsE, offsN, offsG, payE, payN, rxnG,
      emb, W0, att0, xp_h, sn);

  // layer 0
  me_k<<<(N_RXN + 3) / 4, 256, 0, stream>>>(offsE, payE, sn, seAcc0, cntR,
                                            (const uint2*)xp_h, (uint2*)me_h, rstat);
  out_k<false><<<(N_MET + 3) / 4, 256, 0, stream>>>(offsN, payN, sn, rstat,
                                                    (const uint2*)me_h, b0,
                                                    nullptr, nullptr, (uint2*)cur_h);

  // layer 1
  gemm1_k<<<GEMM_BLOCKS, 256, 0, stream>>>(cur_h, W1, att1, xp_h, sn, N_MET);
  me_k<<<(N_RXN + 3) / 4, 256, 0, stream>>>(offsE, payE, sn, seAcc1, cntR,
                                            (const uint2*)xp_h, (uint2*)me_h, rstat);
  out_k<true><<<(N_MET + 3) / 4, 256, 0, stream>>>(offsN, payN, sn, rstat,
                                                   (const uint2*)me_h, b1,
                                                   ln_g, ln_b, (uint2*)cur_h);

  // final readout
  seg_mean_k<2, false><<<(N_RXN + 3) / 4, 256, 0, stream>>>(
      offsE, (const int*)payE, (const uint2*)cur_h, rxnf_h, N_RXN);
  seg_mean_k<1, true><<<(N_GENE + 3) / 4, 256, 0, stream>>>(
      offsG, rxnG, (const uint2*)rxnf_h, out, N_GENE);
}